// Round 5
// baseline (561.379 us; speedup 1.0000x reference)
//
#include <hip/hip_runtime.h>
#include <stdint.h>

// ---- problem constants ----
#define NB 16        // batch
#define NN 4096      // nodes
#define DD 64        // feature dim (== S)
#define EE 32768     // edges (before self loops)
#define ETOT 36864   // edges + self loops
#define ROWS 65536   // B*N
#define KSPLIT 4

typedef _Float16 f16;
typedef f16   half8 __attribute__((ext_vector_type(8)));
typedef f16   f16x8 __attribute__((ext_vector_type(8)));
typedef float f32x4 __attribute__((ext_vector_type(4)));

__device__ __forceinline__ void gload16(const f16* g, f16* l) {
  __builtin_amdgcn_global_load_lds((const __attribute__((address_space(1))) void*)g,
                                   (__attribute__((address_space(3))) void*)l, 16, 0, 0);
}

// ---------------- CSR build ----------------
__global__ __launch_bounds__(256) void k_zero(int* p, int n) {
  int i = blockIdx.x * 256 + threadIdx.x;
  if (i < n) p[i] = 0;
}

__global__ __launch_bounds__(256) void k_count(const int* __restrict__ ei, int* __restrict__ cnt) {
  int t = blockIdx.x * 256 + threadIdx.x;
  if (t >= ETOT) return;
  int d = (t < EE) ? ei[EE + t] : (t - EE);
  atomicAdd(&cnt[d], 1);
}

__global__ __launch_bounds__(256) void k_scan(const int* __restrict__ cnt, int* __restrict__ offs) {
  __shared__ int part[256];
  int t = threadIdx.x;
  int loc[16]; int s = 0;
  #pragma unroll
  for (int i = 0; i < 16; ++i) { int v = cnt[(t << 4) + i]; loc[i] = s; s += v; }
  part[t] = s;
  __syncthreads();
  int own = s;
  for (int d = 1; d < 256; d <<= 1) {
    int u = (t >= d) ? part[t - d] : 0;
    __syncthreads();
    part[t] += u;
    __syncthreads();
  }
  int base = part[t] - own;
  #pragma unroll
  for (int i = 0; i < 16; ++i) offs[(t << 4) + i] = base + loc[i];
}

__global__ __launch_bounds__(256) void k_fill(const int* __restrict__ ei, const int* __restrict__ offs,
                                              int* __restrict__ cur, int* __restrict__ esrc) {
  int t = blockIdx.x * 256 + threadIdx.x;
  if (t >= ETOT) return;
  int s, d;
  if (t < EE) { s = ei[t]; d = ei[EE + t]; } else { s = d = t - EE; }
  int p = atomicAdd(&cur[d], 1);
  esrc[offs[d] + p] = s;
}

// ---------------- seq_linear: h = in^T @ Wseq + b + in^T  (+ fused HT write) ----------------
__global__ __launch_bounds__(256) void k_seq(const float* __restrict__ inp, const float* __restrict__ Wseq,
                                             const float* __restrict__ bseq, float* __restrict__ h,
                                             f16* __restrict__ HT) {
  __shared__ float X[64 * 68];
  int t = threadIdx.x;
  int b = blockIdx.x >> 6, n0 = (blockIdx.x & 63) << 6;
  #pragma unroll
  for (int i = 0; i < 16; ++i) {
    int idx = t + (i << 8);
    int s = idx >> 6, nl = idx & 63;
    X[nl * 68 + s] = inp[((size_t)((b << 6) + s) << 12) + n0 + nl];
  }
  __syncthreads();
  int c = t & 63, rg = t >> 6;
  float Wc[64];
  #pragma unroll
  for (int k = 0; k < 64; ++k) Wc[k] = Wseq[(k << 6) + c];
  float bc = bseq[c];
  float av[16];
  for (int rr = 0; rr < 16; ++rr) {
    int r = (rg << 4) + rr;
    float a = bc + X[r * 68 + c];
    #pragma unroll
    for (int k4 = 0; k4 < 16; ++k4) {
      float4 x = *(const float4*)&X[r * 68 + (k4 << 2)];
      a = fmaf(x.x, Wc[4*k4+0], a); a = fmaf(x.y, Wc[4*k4+1], a);
      a = fmaf(x.z, Wc[4*k4+2], a); a = fmaf(x.w, Wc[4*k4+3], a);
    }
    h[((size_t)(b << 12) + n0 + r) * 64 + c] = a;
    av[rr] = a;
  }
  __syncthreads();
  #pragma unroll
  for (int rr = 0; rr < 16; ++rr) X[((rg << 4) + rr) * 68 + c] = av[rr];
  __syncthreads();
  int nl = t & 63, dg = t >> 6;
  #pragma unroll
  for (int i = 0; i < 16; ++i) {
    int d = (dg << 4) + i;
    HT[((size_t)((b << 6) + d) << 12) + n0 + nl] = (f16)X[nl * 68 + d];
  }
}

// ---------------- adjacency prep: casts ----------------
__global__ __launch_bounds__(256) void k_castSE(const float* __restrict__ SE, f16* __restrict__ SEh) {
  int i = (blockIdx.x * 256 + threadIdx.x) * 4;
  float4 v = *(const float4*)(SE + i);
  f16 o[4] = {(f16)v.x, (f16)v.y, (f16)v.z, (f16)v.w};
  *(uint64_t*)(SEh + i) = *(uint64_t*)o;
}

__global__ __launch_bounds__(256) void k_castTE(const float* __restrict__ TE, f16* __restrict__ TEh) {
  __shared__ float X[64 * 65];
  int t = threadIdx.x;
  int j0 = blockIdx.x << 6;
  #pragma unroll
  for (int i = 0; i < 16; ++i) {
    int idx = t + (i << 8);           // 0..4095 = 64k x 64j
    int k = idx >> 6, jl = idx & 63;
    X[jl * 65 + k] = TE[((size_t)k << 12) + j0 + jl];
  }
  __syncthreads();
  int jl = t >> 2, kg = t & 3;        // 4 threads per output row, 16 k each
  f16 o[16];
  #pragma unroll
  for (int i = 0; i < 16; ++i) o[i] = (f16)X[jl * 65 + (kg << 4) + i];
  f16* dst = TEh + ((size_t)(j0 + jl) << 6) + (kg << 4);
  *(uint64_t*)(dst + 0) = *(uint64_t*)(o + 0);
  *(uint64_t*)(dst + 4) = *(uint64_t*)(o + 4);
  *(uint64_t*)(dst + 8) = *(uint64_t*)(o + 8);
  *(uint64_t*)(dst + 12) = *(uint64_t*)(o + 12);
}

// ---------------- adjacency MFMA GEMM: A = exp(relu(SEh @ TEh^T)) (raw), row partial sums ----------------
__global__ __launch_bounds__(256) void k_adjmm(const f16* __restrict__ SEh, const f16* __restrict__ TEh,
                                               f16* __restrict__ A, float* __restrict__ Zpart) {
  __shared__ f16 Al[128 * 32];
  __shared__ f16 Bl[128 * 32];
  const int t = threadIdx.x, lane = t & 63, w = t >> 6;
  const int m0 = blockIdx.y << 7, j0 = blockIdx.x << 7;
  const int l15 = lane & 15, lhi = lane >> 4;
  const int wm = (w >> 1) << 6, wj = (w & 1) << 6;
  f32x4 acc[4][4] = {};
  const int c0 = (w << 6) + lane;
  const int row0 = c0 >> 2, ko0 = (c0 & 3) << 3;
  const int c1 = c0 + 256;
  const int row1 = c1 >> 2, ko1 = (c1 & 3) << 3;
  const f16* ga0 = SEh + (size_t)(m0 + row0) * 64 + ko0;
  const f16* ga1 = SEh + (size_t)(m0 + row1) * 64 + ko1;
  const f16* gb0 = TEh + (size_t)(j0 + row0) * 64 + ko0;
  const f16* gb1 = TEh + (size_t)(j0 + row1) * 64 + ko1;
  f16* la0 = Al + c0 * 8; f16* la1 = Al + c1 * 8;
  f16* lb0 = Bl + c0 * 8; f16* lb1 = Bl + c1 * 8;
  for (int kt = 0; kt < 2; ++kt) {
    const int kof = kt << 5;
    gload16(ga0 + kof, la0);
    gload16(ga1 + kof, la1);
    gload16(gb0 + kof, lb0);
    gload16(gb1 + kof, lb1);
    __syncthreads();
    half8 af[4], bf[4];
    #pragma unroll
    for (int i = 0; i < 4; ++i) {
      af[i] = *(const half8*)(Al + (wm + i * 16 + l15) * 32 + lhi * 8);
      bf[i] = *(const half8*)(Bl + (wj + i * 16 + l15) * 32 + lhi * 8);
    }
    #pragma unroll
    for (int mi = 0; mi < 4; ++mi)
      #pragma unroll
      for (int nj = 0; nj < 4; ++nj)
        acc[mi][nj] = __builtin_amdgcn_mfma_f32_16x16x32_f16(af[mi], bf[nj], acc[mi][nj], 0, 0, 0);
    __syncthreads();
  }
  // epilogue: e = exp(relu(.)) stored RAW; per-row partial sums (normalization folded into k_gemm)
  float rs[4][4];
  #pragma unroll
  for (int mi = 0; mi < 4; ++mi)
    #pragma unroll
    for (int r = 0; r < 4; ++r) rs[mi][r] = 0.f;
  #pragma unroll
  for (int mi = 0; mi < 4; ++mi)
    #pragma unroll
    for (int nj = 0; nj < 4; ++nj)
      #pragma unroll
      for (int r = 0; r < 4; ++r) {
        int row = m0 + wm + mi * 16 + lhi * 4 + r;
        int col = j0 + wj + nj * 16 + l15;
        float e = __expf(fmaxf(acc[mi][nj][r], 0.f));
        f16 eh = (f16)e;
        A[((size_t)row << 12) + col] = eh;
        rs[mi][r] += (float)eh;      // sum the rounded value for consistency
      }
  #pragma unroll
  for (int mi = 0; mi < 4; ++mi)
    #pragma unroll
    for (int r = 0; r < 4; ++r) {
      float s = rs[mi][r];
      s += __shfl_xor(s, 1); s += __shfl_xor(s, 2);
      s += __shfl_xor(s, 4); s += __shfl_xor(s, 8);
      rs[mi][r] = s;
    }
  if (l15 == 0) {
    int p = (blockIdx.x << 1) + (w & 1);
    #pragma unroll
    for (int mi = 0; mi < 4; ++mi)
      #pragma unroll
      for (int r = 0; r < 4; ++r)
        Zpart[((size_t)p << 12) + m0 + wm + mi * 16 + lhi * 4 + r] = rs[mi][r];
  }
}

__global__ __launch_bounds__(256) void k_rowz(const float* __restrict__ Zpart, float* __restrict__ rowZ) {
  int row = blockIdx.x * 256 + threadIdx.x;
  float s = 0.f;
  #pragma unroll 8
  for (int p = 0; p < 64; ++p) s += Zpart[((size_t)p << 12) + row];
  rowZ[row] = 1.f / s;
}

// ---------------- big GEMM: C[m, j] = rowZ[m] * sum_k Araw[m,k] * BT[j,k] ----------------
// 2-phase double-buffered prefetch, K-split 4, XCD-aware bijective swizzle.
// LDS layout: k-group-outer [ko(4)][row(128)][8 f16] -> conflict-free ds_read_b128.
__global__ __launch_bounds__(256) void k_gemm(const f16* __restrict__ A, const f16* __restrict__ BT,
                                              const float* __restrict__ rowZ, float* __restrict__ Cout) {
  __shared__ f16 Al[2][128 * 32];
  __shared__ f16 Bl[2][128 * 32];
  const int t = threadIdx.x, lane = t & 63, w = t >> 6;
  // XCD swizzle: 1024 wgs, 8 XCDs, 128 contiguous per XCD
  const int wgid = blockIdx.x;
  const int nid = (wgid & 7) * 128 + (wgid >> 3);
  const int z = nid >> 8, rem = nid & 255;
  const int m0 = ((rem >> 3) & 31) << 7, j0 = (rem & 7) << 7;
  const int kbase = z << 10;                       // 1024 K per block
  float* __restrict__ C = Cout + ((size_t)z << 22);
  const int l15 = lane & 15, lhi = lane >> 4;
  const int wm = (w >> 1) << 6, wj = (w & 1) << 6;
  f32x4 acc[4][4] = {};
  // staging: LDS slot s (=c) holds (ko = s>>7, row = s&127); dest linear in lane (required),
  // source pre-permuted so layout lands ko-outer.
  const int c0 = (w << 6) + lane;            // 0..255
  const int c1 = c0 + 256;                   // 256..511
  const int row0 = c0 & 127, ko0 = c0 >> 7;
  const int row1 = c1 & 127, ko1 = c1 >> 7;
  const f16* ga0 = A  + (size_t)(m0 + row0) * 4096 + kbase + ko0 * 8;
  const f16* ga1 = A  + (size_t)(m0 + row1) * 4096 + kbase + ko1 * 8;
  const f16* gb0 = BT + (size_t)(j0 + row0) * 4096 + kbase + ko0 * 8;
  const f16* gb1 = BT + (size_t)(j0 + row1) * 4096 + kbase + ko1 * 8;

  #define STAGE(buf, kt) do {                         \
    const int kof_ = (kt) << 5;                       \
    gload16(ga0 + kof_, Al[buf] + c0 * 8);            \
    gload16(ga1 + kof_, Al[buf] + c1 * 8);            \
    gload16(gb0 + kof_, Bl[buf] + c0 * 8);            \
    gload16(gb1 + kof_, Bl[buf] + c1 * 8);            \
  } while (0)

  STAGE(0, 0);
  __syncthreads();
  const int NKT = 32;              // 1024 / 32
  for (int kt = 0; kt < NKT; ++kt) {
    const int cur = kt & 1;
    if (kt + 1 < NKT) STAGE(cur ^ 1, kt + 1);
    half8 af[4], bf[4];
    #pragma unroll
    for (int i = 0; i < 4; ++i) {
      af[i] = *(const half8*)(Al[cur] + ((lhi << 7) + wm + i * 16 + l15) * 8);
      bf[i] = *(const half8*)(Bl[cur] + ((lhi << 7) + wj + i * 16 + l15) * 8);
    }
    #pragma unroll
    for (int mi = 0; mi < 4; ++mi)
      #pragma unroll
      for (int nj = 0; nj < 4; ++nj)
        acc[mi][nj] = __builtin_amdgcn_mfma_f32_16x16x32_f16(af[mi], bf[nj], acc[mi][nj], 0, 0, 0);
    __syncthreads();
  }
  #undef STAGE
  #pragma unroll
  for (int mi = 0; mi < 4; ++mi) {
    float4 z4 = *(const float4*)&rowZ[m0 + wm + mi * 16 + lhi * 4];
    float ziv[4] = {z4.x, z4.y, z4.z, z4.w};
    #pragma unroll
    for (int nj = 0; nj < 4; ++nj)
      #pragma unroll
      for (int r = 0; r < 4; ++r) {
        int row = m0 + wm + mi * 16 + lhi * 4 + r;
        int col = j0 + wj + nj * 16 + l15;
        C[(size_t)row * 1024 + col] = acc[mi][nj][r] * ziv[r];
      }
  }
}

// ---------------- attention vectors: va/vd[h][k] = sum_c Wg[k,h,c] * a[h][c] ----------------
template<int H>
__global__ __launch_bounds__(256) void k_attv(const float* __restrict__ Wg, const float* __restrict__ asrc,
                                              const float* __restrict__ adst,
                                              float* __restrict__ va, float* __restrict__ vd) {
  int t = threadIdx.x;
  for (int task = t; task < H * 64 * 2; task += 256) {
    int isD = task & 1, idx = task >> 1;     // idx = h*64 + k
    int hh = idx >> 6, k = idx & 63;
    const float* a = (isD ? adst : asrc) + (hh << 6);
    const float* wrow = Wg + (size_t)k * (H * 64) + (hh << 6);
    float s = 0.f;
    #pragma unroll 16
    for (int c = 0; c < 64; ++c) s = fmaf(wrow[c], a[c], s);
    (isD ? vd : va)[idx] = s;
  }
}

// ---------------- xp = h @ Wg (f16 out) + fused als/ald = X . va/vd ----------------
template<int H>
__global__ __launch_bounds__(256) void k_xp(const float* __restrict__ h, const float* __restrict__ Wg,
                                            const float* __restrict__ va, const float* __restrict__ vd,
                                            f16* __restrict__ xp, float* __restrict__ als,
                                            float* __restrict__ ald) {
  __shared__ float X[64 * 68];
  int t = threadIdx.x;
  size_t r0 = (size_t)blockIdx.x << 6;
  #pragma unroll
  for (int i = 0; i < 4; ++i) {
    int idx = t + (i << 8);
    int nl = idx >> 4, d4 = (idx & 15) << 2;
    *(float4*)&X[nl * 68 + d4] = *(const float4*)&h[(r0 + nl) * 64 + d4];
  }
  __syncthreads();
  // fused attention dots (als/ald)
  for (int task = t; task < 64 * 2 * H; task += 256) {
    int row = task & 63, rem = task >> 6;    // rem in [0, 2H)
    int hh = rem >> 1, isD = rem & 1;
    const float* v = (isD ? vd : va) + (hh << 6);
    float s = 0.f;
    #pragma unroll
    for (int k4 = 0; k4 < 16; ++k4) {
      float4 x = *(const float4*)&X[row * 68 + (k4 << 2)];
      s = fmaf(x.x, v[4*k4+0], s); s = fmaf(x.y, v[4*k4+1], s);
      s = fmaf(x.z, v[4*k4+2], s); s = fmaf(x.w, v[4*k4+3], s);
    }
    (isD ? ald : als)[(r0 + row) * H + hh] = s;
  }
  // xp compute
  int c = t & 63, rg = t >> 6;
  for (int hh = 0; hh < H; ++hh) {
    float Wc[64];
    #pragma unroll
    for (int k = 0; k < 64; ++k) Wc[k] = Wg[k * (H * 64) + (hh << 6) + c];
    for (int rr = 0; rr < 16; ++rr) {
      int r = (rg << 4) + rr;
      float a = 0.f;
      #pragma unroll
      for (int k4 = 0; k4 < 16; ++k4) {
        float4 x = *(const float4*)&X[r * 68 + (k4 << 2)];
        a = fmaf(x.x, Wc[4*k4+0], a); a = fmaf(x.y, Wc[4*k4+1], a);
        a = fmaf(x.z, Wc[4*k4+2], a); a = fmaf(x.w, Wc[4*k4+3], a);
      }
      xp[(r0 + r) * (H * 64) + (hh << 6) + c] = (f16)a;
    }
  }
}

// ---------------- GAT aggregation: one wave per (b, node), lane-parallel softmax ----------------
template<int H>
__global__ __launch_bounds__(256) void k_agg(const f16* __restrict__ xp, const float* __restrict__ als,
                                             const float* __restrict__ ald,
                                             const int* __restrict__ offs, const int* __restrict__ cnt,
                                             const int* __restrict__ esrc, const float* __restrict__ bg,
                                             float* __restrict__ hcur) {
  __shared__ float wbuf[4][H * 64];
  __shared__ int   sbuf[4][64];
  int t = threadIdx.x, lane = t & 63, wv = t >> 6;
  int wid = (blockIdx.x << 2) + wv;
  int b = wid >> 12, n = wid & 4095;
  size_t rbase = (size_t)b << 12;
  int o = offs[n], c = cnt[n];
  float aldh[H], m[H], z[H], acc[H];
  #pragma unroll
  for (int hh = 0; hh < H; ++hh) {
    aldh[hh] = ald[(rbase + n) * H + hh];
    m[hh] = -1e30f; z[hh] = 0.f; acc[hh] = 0.f;
  }
  for (int e0 = 0; e0 < c; e0 += 64) {
    int ce = min(64, c - e0);
    // phase 1: lane-parallel ev + weights
    float evl[H]; int sl = 0;
    if (lane < ce) {
      sl = esrc[o + e0 + lane];
      #pragma unroll
      for (int hh = 0; hh < H; ++hh) {
        float ev = als[(rbase + sl) * H + hh] + aldh[hh];
        evl[hh] = ev > 0.f ? ev : 0.2f * ev;
      }
    } else {
      #pragma unroll
      for (int hh = 0; hh < H; ++hh) evl[hh] = -1e30f;
    }
    sbuf[wv][lane] = sl;
    #pragma unroll
    for (int hh = 0; hh < H; ++hh) {
      float v = evl[hh];
      #pragma unroll
      for (int s = 1; s < 64; s <<= 1) v = fmaxf(v, __shfl_xor(v, s));
      float mn = fmaxf(m[hh], v);
      float sc = __expf(m[hh] - mn);
      z[hh] *= sc; acc[hh] *= sc; m[hh] = mn;
      float w = (lane < ce) ? __expf(evl[hh] - mn) : 0.f;
      wbuf[wv][hh * 64 + lane] = w;
      float zs = w;
      #pragma unroll
      for (int s = 1; s < 64; s <<= 1) zs += __shfl_xor(zs, s);
      z[hh] += zs;
    }
    // phase 2: d-parallel aggregation
    for (int e = 0; e < ce; ++e) {
      int s = sbuf[wv][e];
      const f16* row = xp + (rbase + s) * (size_t)(H * 64) + lane;
      #pragma unroll
      for (int hh = 0; hh < H; ++hh)
        acc[hh] = fmaf(wbuf[wv][hh * 64 + e], (float)row[hh << 6], acc[hh]);
    }
  }
  float r = 0.f;
  #pragma unroll
  for (int hh = 0; hh < H; ++hh) r += acc[hh] / z[hh];
  hcur[(rbase + n) * 64 + lane] = r * (1.f / H) + bg[lane];
}

// ---------------- layer-0 combine (+ fused HT write) ----------------
__global__ __launch_bounds__(256) void k_comb0(const float* __restrict__ h, const float* __restrict__ adp,
                                               const float* __restrict__ Wl, const float* __restrict__ bl,
                                               const float* __restrict__ Wo, const float* __restrict__ bo,
                                               float* __restrict__ hout, f16* __restrict__ HT) {
  __shared__ float Xa[64 * 68];
  __shared__ float Xh[64 * 68];
  int t = threadIdx.x;
  int b = blockIdx.x >> 6, n0 = (blockIdx.x & 63) << 6;
  #pragma unroll
  for (int i = 0; i < 4; ++i) {
    int idx = t + (i << 8);
    int nl = idx >> 4, d4 = (idx & 15) << 2;
    size_t arow = ((size_t)(n0 + nl) << 10) + (b << 6) + d4;
    float4 s = *(const float4*)&adp[arow];
    #pragma unroll
    for (int p = 1; p < KSPLIT; ++p) {
      float4 q = *(const float4*)&adp[arow + (size_t)p * (4096 * 1024)];
      s.x += q.x; s.y += q.y; s.z += q.z; s.w += q.w;
    }
    *(float4*)&Xa[nl * 68 + d4] = s;
    *(float4*)&Xh[nl * 68 + d4] = *(const float4*)&h[((size_t)(b << 12) + n0 + nl) * 64 + d4];
  }
  __syncthreads();
  int c = t & 63, rg = t >> 6;
  float blc = bl[c], boc = bo[c];
  float Wc[64], gv[16], fv[16];
  #pragma unroll
  for (int k = 0; k < 64; ++k) Wc[k] = Wl[(k << 6) + c];
  for (int rr = 0; rr < 16; ++rr) {
    int r = (rg << 4) + rr;
    float ag = blc;
    #pragma unroll
    for (int k4 = 0; k4 < 16; ++k4) {
      float4 x = *(const float4*)&Xa[r * 68 + (k4 << 2)];
      ag = fmaf(x.x, Wc[4*k4+0], ag); ag = fmaf(x.y, Wc[4*k4+1], ag);
      ag = fmaf(x.z, Wc[4*k4+2], ag); ag = fmaf(x.w, Wc[4*k4+3], ag);
    }
    gv[rr] = 1.f / (1.f + __expf(-ag));
  }
  #pragma unroll
  for (int k = 0; k < 64; ++k) Wc[k] = Wo[(k << 6) + c];
  for (int rr = 0; rr < 16; ++rr) {
    int r = (rg << 4) + rr;
    float ao = boc;
    #pragma unroll
    for (int k4 = 0; k4 < 16; ++k4) {
      float4 x = *(const float4*)&Xh[r * 68 + (k4 << 2)];
      ao = fmaf(x.x, Wc[4*k4+0], ao); ao = fmaf(x.y, Wc[4*k4+1], ao);
      ao = fmaf(x.z, Wc[4*k4+2], ao); ao = fmaf(x.w, Wc[4*k4+3], ao);
    }
    float hv = Xh[r * 68 + c];
    float g = gv[rr];
    float val = tanhf(hv) * g + ao * (1.f - g);
    hout[((size_t)(b << 12) + n0 + r) * 64 + c] = val;
    fv[rr] = val;
  }
  __syncthreads();
  #pragma unroll
  for (int rr = 0; rr < 16; ++rr) Xh[((rg << 4) + rr) * 68 + c] = fv[rr];
  __syncthreads();
  int nl = t & 63, dg = t >> 6;
  #pragma unroll
  for (int i = 0; i < 16; ++i) {
    int d = (dg << 4) + i;
    HT[((size_t)((b << 6) + d) << 12) + n0 + nl] = (f16)Xh[nl * 68 + d];
  }
}

// ---------------- layer-1/2 combine (+ optional fused HT write) ----------------
template<int ACT, bool WRT>   // ACT 0: leaky 0.01, 1: relu
__global__ __launch_bounds__(256) void k_comb12(const float* __restrict__ h, const float* __restrict__ adp,
                                                const float* __restrict__ hcur, const float* __restrict__ Wl,
                                                const float* __restrict__ bl, float* __restrict__ hout,
                                                f16* __restrict__ HT) {
  __shared__ float Xa[64 * 68];
  int t = threadIdx.x;
  int b = blockIdx.x >> 6, n0 = (blockIdx.x & 63) << 6;
  #pragma unroll
  for (int i = 0; i < 4; ++i) {
    int idx = t + (i << 8);
    int nl = idx >> 4, d4 = (idx & 15) << 2;
    size_t arow = ((size_t)(n0 + nl) << 10) + (b << 6) + d4;
    float4 s = *(const float4*)&adp[arow];
    #pragma unroll
    for (int p = 1; p < KSPLIT; ++p) {
      float4 q = *(const float4*)&adp[arow + (size_t)p * (4096 * 1024)];
      s.x += q.x; s.y += q.y; s.z += q.z; s.w += q.w;
    }
    *(float4*)&Xa[nl * 68 + d4] = s;
  }
  __syncthreads();
  int c = t & 63, rg = t >> 6;
  float Wc[64];
  #pragma unroll
  for (int k = 0; k < 64; ++k) Wc[k] = Wl[(k << 6) + c];
  float blc = bl[c];
  float fv[16];
  for (int rr = 0; rr < 16; ++rr) {
    int r = (rg << 4) + rr;
    float ag = blc;
    #pragma unroll
    for (int k4 = 0; k4 < 16; ++k4) {
      float4 x = *(const float4*)&Xa[r * 68 + (k4 << 2)];
      ag = fmaf(x.x, Wc[4*k4+0], ag); ag = fmaf(x.y, Wc[4*k4+1], ag);
      ag = fmaf(x.z, Wc[4*k4+2], ag); ag = fmaf(x.w, Wc[4*k4+3], ag);
    }
    float g = 1.f / (1.f + __expf(-ag));
    size_t ridx = ((size_t)(b << 12) + n0 + r) * 64 + c;
    float hv = h[ridx], cv = hcur[ridx];
    float act = ACT ? fmaxf(cv, 0.f) : (cv > 0.f ? cv : 0.01f * cv);
    float val = act * g + hv * (1.f - g);
    hout[ridx] = val;
    fv[rr] = val;
  }
  if (WRT) {
    __syncthreads();
    #pragma unroll
    for (int rr = 0; rr < 16; ++rr) Xa[((rg << 4) + rr) * 68 + c] = fv[rr];
    __syncthreads();
    int nl = t & 63, dg = t >> 6;
    #pragma unroll
    for (int i = 0; i < 16; ++i) {
      int d = (dg << 4) + i;
      HT[((size_t)((b << 6) + d) << 12) + n0 + nl] = (f16)Xa[nl * 68 + d];
    }
  }
}

// ---------------- host launch ----------------
extern "C" void kernel_launch(void* const* d_in, const int* in_sizes, int n_in,
                              void* d_out, int out_size, void* d_ws, size_t ws_size,
                              hipStream_t stream) {
  (void)in_sizes; (void)n_in; (void)out_size; (void)ws_size;
  const float* inp  = (const float*)d_in[0];
  const int*   ei   = (const int*)d_in[1];
  const float* Wseq = (const float*)d_in[2];
  const float* bseq = (const float*)d_in[3];
  const float* SE   = (const float*)d_in[4];
  const float* TE   = (const float*)d_in[5];
  const float* Wg[3]   = {(const float*)d_in[6],  (const float*)d_in[12], (const float*)d_in[18]};
  const float* asrc[3] = {(const float*)d_in[7],  (const float*)d_in[13], (const float*)d_in[19]};
  const float* adst[3] = {(const float*)d_in[8],  (const float*)d_in[14], (const float*)d_in[20]};
  const float* bgp[3]  = {(const float*)d_in[9],  (const float*)d_in[15], (const float*)d_in[21]};
  const float* Wl[3]   = {(const float*)d_in[10], (const float*)d_in[16], (const float*)d_in[22]};
  const float* bl[3]   = {(const float*)d_in[11], (const float*)d_in[17], (const float*)d_in[23]};
  const float* Wo = (const float*)d_in[24];
  const float* bo = (const float*)d_in[25];
  float* out = (float*)d_out;

  uint8_t* ws = (uint8_t*)d_ws;
  size_t o = 0;
  auto nxt = [&](size_t sz) { void* p = ws + o; o += (sz + 255) & ~(size_t)255; return p; };
  f16*   Af   = (f16*)  nxt((size_t)NN * NN * sizeof(f16));        // 32 MB
  f16*   HT   = (f16*)  nxt((size_t)1024 * NN * sizeof(f16));      // 8 MB
  float* h    = (float*)nxt((size_t)ROWS * 64 * 4);                // 16 MB
  float* adp  = (float*)nxt((size_t)KSPLIT * NN * 1024 * 4);       // 64 MB (4 k-split parts)
  f16*   xp   = (f16*)  nxt((size_t)ROWS * 192 * sizeof(f16));     // 24 MB
  float* als  = (float*)nxt((size_t)ROWS * 3 * 4);
  float* ald  = (float*)nxt((size_t)ROWS * 3 * 4);
  float* hcur = (float*)nxt((size_t)ROWS * 64 * 4);                // 16 MB
  float* rowZ = (float*)nxt((size_t)NN * 4);
  float* Zpart= (float*)nxt((size_t)64 * NN * 4);                  // 1 MB
  f16*   SEh  = (f16*)  nxt((size_t)NN * 64 * sizeof(f16));
  f16*   TEh  = (f16*)  nxt((size_t)NN * 64 * sizeof(f16));
  float* va   = (float*)nxt((size_t)3 * 64 * 4);
  float* vd   = (float*)nxt((size_t)3 * 64 * 4);
  int*   cnt  = (int*)  nxt((size_t)NN * 4);
  int*   curp = (int*)  nxt((size_t)NN * 4);
  int*   offs = (int*)  nxt((size_t)NN * 4);
  int*   esrc = (int*)  nxt((size_t)ETOT * 4);

  dim3 blk(256);
  // CSR build
  k_zero<<<16, blk, 0, stream>>>(cnt, NN);
  k_zero<<<16, blk, 0, stream>>>(curp, NN);
  k_count<<<144, blk, 0, stream>>>(ei, cnt);
  k_scan<<<1, blk, 0, stream>>>(cnt, offs);
  k_fill<<<144, blk, 0, stream>>>(ei, offs, curp, esrc);
  // h0 (+HT) + adjacency (MFMA path, raw exp + rowZ)
  k_seq<<<1024, blk, 0, stream>>>(inp, Wseq, bseq, h, HT);
  k_castSE<<<256, blk, 0, stream>>>(SE, SEh);
  k_castTE<<<64, blk, 0, stream>>>(TE, TEh);
  k_adjmm<<<dim3(32, 32), blk, 0, stream>>>(SEh, TEh, Af, Zpart);
  k_rowz<<<16, blk, 0, stream>>>(Zpart, rowZ);
  // ---- layer 0 ----
  k_gemm<<<1024, blk, 0, stream>>>(Af, HT, rowZ, adp);
  k_comb0<<<1024, blk, 0, stream>>>(h, adp, Wl[0], bl[0], Wo, bo, h, HT);
  // ---- layer 1 ----
  k_attv<3><<<1, blk, 0, stream>>>(Wg[1], asrc[1], adst[1], va, vd);
  k_xp<3><<<1024, blk, 0, stream>>>(h, Wg[1], va, vd, xp, als, ald);
  k_gemm<<<1024, blk, 0, stream>>>(Af, HT, rowZ, adp);
  k_agg<3><<<16384, blk, 0, stream>>>(xp, als, ald, offs, cnt, esrc, bgp[1], hcur);
  k_comb12<0, true><<<1024, blk, 0, stream>>>(h, adp, hcur, Wl[1], bl[1], h, HT);
  // ---- layer 2 ----
  k_attv<1><<<1, blk, 0, stream>>>(Wg[2], asrc[2], adst[2], va, vd);
  k_xp<1><<<1024, blk, 0, stream>>>(h, Wg[2], va, vd, xp, als, ald);
  k_gemm<<<1024, blk, 0, stream>>>(Af, HT, rowZ, adp);
  k_agg<1><<<16384, blk, 0, stream>>>(xp, als, ald, offs, cnt, esrc, bgp[2], hcur);
  k_comb12<1, false><<<1024, blk, 0, stream>>>(h, adp, hcur, Wl[2], bl[2], out, (f16*)nullptr);
}

// Round 6
// 478.652 us; speedup vs baseline: 1.1728x; 1.1728x over previous
//
#include <hip/hip_runtime.h>
#include <stdint.h>

// ---- problem constants ----
#define NB 16        // batch
#define NN 4096      // nodes
#define DD 64        // feature dim (== S)
#define EE 32768     // edges (before self loops)
#define ETOT 36864   // edges + self loops
#define ROWS 65536   // B*N
#define KSPLIT 4

typedef _Float16 f16;
typedef f16   half8 __attribute__((ext_vector_type(8)));
typedef f16   f16x8 __attribute__((ext_vector_type(8)));
typedef float f32x4 __attribute__((ext_vector_type(4)));

__device__ __forceinline__ void gload16(const f16* g, f16* l) {
  __builtin_amdgcn_global_load_lds((const __attribute__((address_space(1))) void*)g,
                                   (__attribute__((address_space(3))) void*)l, 16, 0, 0);
}

// ---------------- CSR build ----------------
__global__ __launch_bounds__(256) void k_zero(int* p, int n) {
  int i = blockIdx.x * 256 + threadIdx.x;
  if (i < n) p[i] = 0;
}

__global__ __launch_bounds__(256) void k_count(const int* __restrict__ ei, int* __restrict__ cnt) {
  int t = blockIdx.x * 256 + threadIdx.x;
  if (t >= ETOT) return;
  int d = (t < EE) ? ei[EE + t] : (t - EE);
  atomicAdd(&cnt[d], 1);
}

__global__ __launch_bounds__(256) void k_scan(const int* __restrict__ cnt, int* __restrict__ offs) {
  __shared__ int part[256];
  int t = threadIdx.x;
  int loc[16]; int s = 0;
  #pragma unroll
  for (int i = 0; i < 16; ++i) { int v = cnt[(t << 4) + i]; loc[i] = s; s += v; }
  part[t] = s;
  __syncthreads();
  int own = s;
  for (int d = 1; d < 256; d <<= 1) {
    int u = (t >= d) ? part[t - d] : 0;
    __syncthreads();
    part[t] += u;
    __syncthreads();
  }
  int base = part[t] - own;
  #pragma unroll
  for (int i = 0; i < 16; ++i) offs[(t << 4) + i] = base + loc[i];
}

__global__ __launch_bounds__(256) void k_fill(const int* __restrict__ ei, const int* __restrict__ offs,
                                              int* __restrict__ cur, int* __restrict__ esrc) {
  int t = blockIdx.x * 256 + threadIdx.x;
  if (t >= ETOT) return;
  int s, d;
  if (t < EE) { s = ei[t]; d = ei[EE + t]; } else { s = d = t - EE; }
  int p = atomicAdd(&cur[d], 1);
  esrc[offs[d] + p] = s;
}

// ---------------- seq_linear: h = in^T @ Wseq + b + in^T  (+ fused HT write) ----------------
__global__ __launch_bounds__(256) void k_seq(const float* __restrict__ inp, const float* __restrict__ Wseq,
                                             const float* __restrict__ bseq, float* __restrict__ h,
                                             f16* __restrict__ HT) {
  __shared__ float X[64 * 68];
  int t = threadIdx.x;
  int b = blockIdx.x >> 6, n0 = (blockIdx.x & 63) << 6;
  #pragma unroll
  for (int i = 0; i < 16; ++i) {
    int idx = t + (i << 8);
    int s = idx >> 6, nl = idx & 63;
    X[nl * 68 + s] = inp[((size_t)((b << 6) + s) << 12) + n0 + nl];
  }
  __syncthreads();
  int c = t & 63, rg = t >> 6;
  float Wc[64];
  #pragma unroll
  for (int k = 0; k < 64; ++k) Wc[k] = Wseq[(k << 6) + c];
  float bc = bseq[c];
  float av[16];
  for (int rr = 0; rr < 16; ++rr) {
    int r = (rg << 4) + rr;
    float a = bc + X[r * 68 + c];
    #pragma unroll
    for (int k4 = 0; k4 < 16; ++k4) {
      float4 x = *(const float4*)&X[r * 68 + (k4 << 2)];
      a = fmaf(x.x, Wc[4*k4+0], a); a = fmaf(x.y, Wc[4*k4+1], a);
      a = fmaf(x.z, Wc[4*k4+2], a); a = fmaf(x.w, Wc[4*k4+3], a);
    }
    h[((size_t)(b << 12) + n0 + r) * 64 + c] = a;
    av[rr] = a;
  }
  __syncthreads();
  #pragma unroll
  for (int rr = 0; rr < 16; ++rr) X[((rg << 4) + rr) * 68 + c] = av[rr];
  __syncthreads();
  int nl = t & 63, dg = t >> 6;
  #pragma unroll
  for (int i = 0; i < 16; ++i) {
    int d = (dg << 4) + i;
    HT[((size_t)((b << 6) + d) << 12) + n0 + nl] = (f16)X[nl * 68 + d];
  }
}

// ---------------- adjacency prep: casts ----------------
__global__ __launch_bounds__(256) void k_castSE(const float* __restrict__ SE, f16* __restrict__ SEh) {
  int i = (blockIdx.x * 256 + threadIdx.x) * 4;
  float4 v = *(const float4*)(SE + i);
  f16 o[4] = {(f16)v.x, (f16)v.y, (f16)v.z, (f16)v.w};
  *(uint64_t*)(SEh + i) = *(uint64_t*)o;
}

__global__ __launch_bounds__(256) void k_castTE(const float* __restrict__ TE, f16* __restrict__ TEh) {
  __shared__ float X[64 * 65];
  int t = threadIdx.x;
  int j0 = blockIdx.x << 6;
  #pragma unroll
  for (int i = 0; i < 16; ++i) {
    int idx = t + (i << 8);           // 0..4095 = 64k x 64j
    int k = idx >> 6, jl = idx & 63;
    X[jl * 65 + k] = TE[((size_t)k << 12) + j0 + jl];
  }
  __syncthreads();
  int jl = t >> 2, kg = t & 3;        // 4 threads per output row, 16 k each
  f16 o[16];
  #pragma unroll
  for (int i = 0; i < 16; ++i) o[i] = (f16)X[jl * 65 + (kg << 4) + i];
  f16* dst = TEh + ((size_t)(j0 + jl) << 6) + (kg << 4);
  *(uint64_t*)(dst + 0) = *(uint64_t*)(o + 0);
  *(uint64_t*)(dst + 4) = *(uint64_t*)(o + 4);
  *(uint64_t*)(dst + 8) = *(uint64_t*)(o + 8);
  *(uint64_t*)(dst + 12) = *(uint64_t*)(o + 12);
}

// ---------------- adjacency MFMA GEMM: A = exp(relu(SEh @ TEh^T)) (raw), row partial sums ----------------
__global__ __launch_bounds__(256) void k_adjmm(const f16* __restrict__ SEh, const f16* __restrict__ TEh,
                                               f16* __restrict__ A, float* __restrict__ Zpart) {
  __shared__ f16 Al[128 * 32];
  __shared__ f16 Bl[128 * 32];
  const int t = threadIdx.x, lane = t & 63, w = t >> 6;
  const int m0 = blockIdx.y << 7, j0 = blockIdx.x << 7;
  const int l15 = lane & 15, lhi = lane >> 4;
  const int wm = (w >> 1) << 6, wj = (w & 1) << 6;
  f32x4 acc[4][4] = {};
  const int c0 = (w << 6) + lane;
  const int row0 = c0 >> 2, ko0 = (c0 & 3) << 3;
  const int c1 = c0 + 256;
  const int row1 = c1 >> 2, ko1 = (c1 & 3) << 3;
  const f16* ga0 = SEh + (size_t)(m0 + row0) * 64 + ko0;
  const f16* ga1 = SEh + (size_t)(m0 + row1) * 64 + ko1;
  const f16* gb0 = TEh + (size_t)(j0 + row0) * 64 + ko0;
  const f16* gb1 = TEh + (size_t)(j0 + row1) * 64 + ko1;
  f16* la0 = Al + c0 * 8; f16* la1 = Al + c1 * 8;
  f16* lb0 = Bl + c0 * 8; f16* lb1 = Bl + c1 * 8;
  for (int kt = 0; kt < 2; ++kt) {
    const int kof = kt << 5;
    gload16(ga0 + kof, la0);
    gload16(ga1 + kof, la1);
    gload16(gb0 + kof, lb0);
    gload16(gb1 + kof, lb1);
    __syncthreads();
    half8 af[4], bf[4];
    #pragma unroll
    for (int i = 0; i < 4; ++i) {
      af[i] = *(const half8*)(Al + (wm + i * 16 + l15) * 32 + lhi * 8);
      bf[i] = *(const half8*)(Bl + (wj + i * 16 + l15) * 32 + lhi * 8);
    }
    #pragma unroll
    for (int mi = 0; mi < 4; ++mi)
      #pragma unroll
      for (int nj = 0; nj < 4; ++nj)
        acc[mi][nj] = __builtin_amdgcn_mfma_f32_16x16x32_f16(af[mi], bf[nj], acc[mi][nj], 0, 0, 0);
    __syncthreads();
  }
  // epilogue: e = exp(relu(.)) stored RAW; per-row partial sums (normalization folded into k_gemm)
  float rs[4][4];
  #pragma unroll
  for (int mi = 0; mi < 4; ++mi)
    #pragma unroll
    for (int r = 0; r < 4; ++r) rs[mi][r] = 0.f;
  #pragma unroll
  for (int mi = 0; mi < 4; ++mi)
    #pragma unroll
    for (int nj = 0; nj < 4; ++nj)
      #pragma unroll
      for (int r = 0; r < 4; ++r) {
        int row = m0 + wm + mi * 16 + lhi * 4 + r;
        int col = j0 + wj + nj * 16 + l15;
        float e = __expf(fmaxf(acc[mi][nj][r], 0.f));
        f16 eh = (f16)e;
        A[((size_t)row << 12) + col] = eh;
        rs[mi][r] += (float)eh;      // sum the rounded value for consistency
      }
  #pragma unroll
  for (int mi = 0; mi < 4; ++mi)
    #pragma unroll
    for (int r = 0; r < 4; ++r) {
      float s = rs[mi][r];
      s += __shfl_xor(s, 1); s += __shfl_xor(s, 2);
      s += __shfl_xor(s, 4); s += __shfl_xor(s, 8);
      rs[mi][r] = s;
    }
  if (l15 == 0) {
    int p = (blockIdx.x << 1) + (w & 1);
    #pragma unroll
    for (int mi = 0; mi < 4; ++mi)
      #pragma unroll
      for (int r = 0; r < 4; ++r)
        Zpart[((size_t)p << 12) + m0 + wm + mi * 16 + lhi * 4 + r] = rs[mi][r];
  }
}

__global__ __launch_bounds__(256) void k_rowz(const float* __restrict__ Zpart, float* __restrict__ rowZ) {
  int row = blockIdx.x * 256 + threadIdx.x;
  float s = 0.f;
  #pragma unroll 8
  for (int p = 0; p < 64; ++p) s += Zpart[((size_t)p << 12) + row];
  rowZ[row] = 1.f / s;
}

// ---------------- big GEMM: C[m, j] = rowZ[m] * sum_k Araw[m,k] * BT[j,k] ----------------
// 2-phase double-buffered prefetch, K-split 4, XCD swizzle.
// LDS: linear dest; slot s holds (row = s>>2, ko = (s&3) ^ ((row>>1)&3)) -- XOR swizzle applied
// to the pre-permuted GLOBAL source (write side) and to the ds_read address (read side).
// Global: each 4-lane group still covers one row's 64B line (R4 coalescing); reads 2-way banked (free).
__global__ __launch_bounds__(256) void k_gemm(const f16* __restrict__ A, const f16* __restrict__ BT,
                                              const float* __restrict__ rowZ, float* __restrict__ Cout) {
  __shared__ f16 Al[2][128 * 32];
  __shared__ f16 Bl[2][128 * 32];
  const int t = threadIdx.x, lane = t & 63, w = t >> 6;
  // XCD swizzle: 1024 wgs, 8 XCDs, 128 contiguous per XCD
  const int wgid = blockIdx.x;
  const int nid = (wgid & 7) * 128 + (wgid >> 3);
  const int z = nid >> 8, rem = nid & 255;
  const int m0 = ((rem >> 3) & 31) << 7, j0 = (rem & 7) << 7;
  const int kbase = z << 10;                       // 1024 K per block
  float* __restrict__ C = Cout + ((size_t)z << 22);
  const int l15 = lane & 15, lhi = lane >> 4;
  const int wm = (w >> 1) << 6, wj = (w & 1) << 6;
  f32x4 acc[4][4] = {};
  const int c0 = (w << 6) + lane;            // 0..255
  const int c1 = c0 + 256;                   // 256..511
  const int row0 = c0 >> 2, ko0 = (c0 & 3) ^ ((row0 >> 1) & 3);
  const int row1 = c1 >> 2, ko1 = (c1 & 3) ^ ((row1 >> 1) & 3);
  const f16* ga0 = A  + (size_t)(m0 + row0) * 4096 + kbase + ko0 * 8;
  const f16* ga1 = A  + (size_t)(m0 + row1) * 4096 + kbase + ko1 * 8;
  const f16* gb0 = BT + (size_t)(j0 + row0) * 4096 + kbase + ko0 * 8;
  const f16* gb1 = BT + (size_t)(j0 + row1) * 4096 + kbase + ko1 * 8;

  #define STAGE(buf, kt) do {                         \
    const int kof_ = (kt) << 5;                       \
    gload16(ga0 + kof_, Al[buf] + c0 * 8);            \
    gload16(ga1 + kof_, Al[buf] + c1 * 8);            \
    gload16(gb0 + kof_, Bl[buf] + c0 * 8);            \
    gload16(gb1 + kof_, Bl[buf] + c1 * 8);            \
  } while (0)

  STAGE(0, 0);
  __syncthreads();
  const int NKT = 32;              // 1024 / 32
  for (int kt = 0; kt < NKT; ++kt) {
    const int cur = kt & 1;
    if (kt + 1 < NKT) STAGE(cur ^ 1, kt + 1);
    half8 af[4], bf[4];
    #pragma unroll
    for (int i = 0; i < 4; ++i) {
      const int ra = wm + i * 16 + l15;
      const int rb = wj + i * 16 + l15;
      af[i] = *(const half8*)(Al[cur] + (((ra << 2) + (lhi ^ ((ra >> 1) & 3)))) * 8);
      bf[i] = *(const half8*)(Bl[cur] + (((rb << 2) + (lhi ^ ((rb >> 1) & 3)))) * 8);
    }
    #pragma unroll
    for (int mi = 0; mi < 4; ++mi)
      #pragma unroll
      for (int nj = 0; nj < 4; ++nj)
        acc[mi][nj] = __builtin_amdgcn_mfma_f32_16x16x32_f16(af[mi], bf[nj], acc[mi][nj], 0, 0, 0);
    __syncthreads();
  }
  #undef STAGE
  #pragma unroll
  for (int mi = 0; mi < 4; ++mi) {
    float4 z4 = *(const float4*)&rowZ[m0 + wm + mi * 16 + lhi * 4];
    float ziv[4] = {z4.x, z4.y, z4.z, z4.w};
    #pragma unroll
    for (int nj = 0; nj < 4; ++nj)
      #pragma unroll
      for (int r = 0; r < 4; ++r) {
        int row = m0 + wm + mi * 16 + lhi * 4 + r;
        int col = j0 + wj + nj * 16 + l15;
        C[(size_t)row * 1024 + col] = acc[mi][nj][r] * ziv[r];
      }
  }
}

// ---------------- attention vectors: va/vd[h][k] = sum_c Wg[k,h,c] * a[h][c] ----------------
template<int H>
__global__ __launch_bounds__(256) void k_attv(const float* __restrict__ Wg, const float* __restrict__ asrc,
                                              const float* __restrict__ adst,
                                              float* __restrict__ va, float* __restrict__ vd) {
  int t = threadIdx.x;
  for (int task = t; task < H * 64 * 2; task += 256) {
    int isD = task & 1, idx = task >> 1;     // idx = h*64 + k
    int hh = idx >> 6, k = idx & 63;
    const float* a = (isD ? adst : asrc) + (hh << 6);
    const float* wrow = Wg + (size_t)k * (H * 64) + (hh << 6);
    float s = 0.f;
    #pragma unroll 16
    for (int c = 0; c < 64; ++c) s = fmaf(wrow[c], a[c], s);
    (isD ? vd : va)[idx] = s;
  }
}

// ---------------- xp = h @ Wg (f16 out) + fused als/ald = X . va/vd ----------------
template<int H>
__global__ __launch_bounds__(256) void k_xp(const float* __restrict__ h, const float* __restrict__ Wg,
                                            const float* __restrict__ va, const float* __restrict__ vd,
                                            f16* __restrict__ xp, float* __restrict__ als,
                                            float* __restrict__ ald) {
  __shared__ float X[64 * 68];
  int t = threadIdx.x;
  size_t r0 = (size_t)blockIdx.x << 6;
  #pragma unroll
  for (int i = 0; i < 4; ++i) {
    int idx = t + (i << 8);
    int nl = idx >> 4, d4 = (idx & 15) << 2;
    *(float4*)&X[nl * 68 + d4] = *(const float4*)&h[(r0 + nl) * 64 + d4];
  }
  __syncthreads();
  // fused attention dots (als/ald)
  for (int task = t; task < 64 * 2 * H; task += 256) {
    int row = task & 63, rem = task >> 6;    // rem in [0, 2H)
    int hh = rem >> 1, isD = rem & 1;
    const float* v = (isD ? vd : va) + (hh << 6);
    float s = 0.f;
    #pragma unroll
    for (int k4 = 0; k4 < 16; ++k4) {
      float4 x = *(const float4*)&X[row * 68 + (k4 << 2)];
      s = fmaf(x.x, v[4*k4+0], s); s = fmaf(x.y, v[4*k4+1], s);
      s = fmaf(x.z, v[4*k4+2], s); s = fmaf(x.w, v[4*k4+3], s);
    }
    (isD ? ald : als)[(r0 + row) * H + hh] = s;
  }
  // xp compute
  int c = t & 63, rg = t >> 6;
  for (int hh = 0; hh < H; ++hh) {
    float Wc[64];
    #pragma unroll
    for (int k = 0; k < 64; ++k) Wc[k] = Wg[k * (H * 64) + (hh << 6) + c];
    for (int rr = 0; rr < 16; ++rr) {
      int r = (rg << 4) + rr;
      float a = 0.f;
      #pragma unroll
      for (int k4 = 0; k4 < 16; ++k4) {
        float4 x = *(const float4*)&X[r * 68 + (k4 << 2)];
        a = fmaf(x.x, Wc[4*k4+0], a); a = fmaf(x.y, Wc[4*k4+1], a);
        a = fmaf(x.z, Wc[4*k4+2], a); a = fmaf(x.w, Wc[4*k4+3], a);
      }
      xp[(r0 + r) * (H * 64) + (hh << 6) + c] = (f16)a;
    }
  }
}

// ---------------- GAT aggregation: one wave per (b, node), lane-parallel softmax ----------------
template<int H>
__global__ __launch_bounds__(256) void k_agg(const f16* __restrict__ xp, const float* __restrict__ als,
                                             const float* __restrict__ ald,
                                             const int* __restrict__ offs, const int* __restrict__ cnt,
                                             const int* __restrict__ esrc, const float* __restrict__ bg,
                                             float* __restrict__ hcur) {
  __shared__ float wbuf[4][H * 64];
  __shared__ int   sbuf[4][64];
  int t = threadIdx.x, lane = t & 63, wv = t >> 6;
  int wid = (blockIdx.x << 2) + wv;
  int b = wid >> 12, n = wid & 4095;
  size_t rbase = (size_t)b << 12;
  int o = offs[n], c = cnt[n];
  float aldh[H], m[H], z[H], acc[H];
  #pragma unroll
  for (int hh = 0; hh < H; ++hh) {
    aldh[hh] = ald[(rbase + n) * H + hh];
    m[hh] = -1e30f; z[hh] = 0.f; acc[hh] = 0.f;
  }
  for (int e0 = 0; e0 < c; e0 += 64) {
    int ce = min(64, c - e0);
    // phase 1: lane-parallel ev + weights
    float evl[H]; int sl = 0;
    if (lane < ce) {
      sl = esrc[o + e0 + lane];
      #pragma unroll
      for (int hh = 0; hh < H; ++hh) {
        float ev = als[(rbase + sl) * H + hh] + aldh[hh];
        evl[hh] = ev > 0.f ? ev : 0.2f * ev;
      }
    } else {
      #pragma unroll
      for (int hh = 0; hh < H; ++hh) evl[hh] = -1e30f;
    }
    sbuf[wv][lane] = sl;
    #pragma unroll
    for (int hh = 0; hh < H; ++hh) {
      float v = evl[hh];
      #pragma unroll
      for (int s = 1; s < 64; s <<= 1) v = fmaxf(v, __shfl_xor(v, s));
      float mn = fmaxf(m[hh], v);
      float sc = __expf(m[hh] - mn);
      z[hh] *= sc; acc[hh] *= sc; m[hh] = mn;
      float w = (lane < ce) ? __expf(evl[hh] - mn) : 0.f;
      wbuf[wv][hh * 64 + lane] = w;
      float zs = w;
      #pragma unroll
      for (int s = 1; s < 64; s <<= 1) zs += __shfl_xor(zs, s);
      z[hh] += zs;
    }
    // phase 2: d-parallel aggregation
    for (int e = 0; e < ce; ++e) {
      int s = sbuf[wv][e];
      const f16* row = xp + (rbase + s) * (size_t)(H * 64) + lane;
      #pragma unroll
      for (int hh = 0; hh < H; ++hh)
        acc[hh] = fmaf(wbuf[wv][hh * 64 + e], (float)row[hh << 6], acc[hh]);
    }
  }
  float r = 0.f;
  #pragma unroll
  for (int hh = 0; hh < H; ++hh) r += acc[hh] / z[hh];
  hcur[(rbase + n) * 64 + lane] = r * (1.f / H) + bg[lane];
}

// ---------------- layer-0 combine (+ fused HT write) ----------------
__global__ __launch_bounds__(256) void k_comb0(const float* __restrict__ h, const float* __restrict__ adp,
                                               const float* __restrict__ Wl, const float* __restrict__ bl,
                                               const float* __restrict__ Wo, const float* __restrict__ bo,
                                               float* __restrict__ hout, f16* __restrict__ HT) {
  __shared__ float Xa[64 * 68];
  __shared__ float Xh[64 * 68];
  int t = threadIdx.x;
  int b = blockIdx.x >> 6, n0 = (blockIdx.x & 63) << 6;
  #pragma unroll
  for (int i = 0; i < 4; ++i) {
    int idx = t + (i << 8);
    int nl = idx >> 4, d4 = (idx & 15) << 2;
    size_t arow = ((size_t)(n0 + nl) << 10) + (b << 6) + d4;
    float4 s = *(const float4*)&adp[arow];
    #pragma unroll
    for (int p = 1; p < KSPLIT; ++p) {
      float4 q = *(const float4*)&adp[arow + (size_t)p * (4096 * 1024)];
      s.x += q.x; s.y += q.y; s.z += q.z; s.w += q.w;
    }
    *(float4*)&Xa[nl * 68 + d4] = s;
    *(float4*)&Xh[nl * 68 + d4] = *(const float4*)&h[((size_t)(b << 12) + n0 + nl) * 64 + d4];
  }
  __syncthreads();
  int c = t & 63, rg = t >> 6;
  float blc = bl[c], boc = bo[c];
  float Wc[64], gv[16], fv[16];
  #pragma unroll
  for (int k = 0; k < 64; ++k) Wc[k] = Wl[(k << 6) + c];
  for (int rr = 0; rr < 16; ++rr) {
    int r = (rg << 4) + rr;
    float ag = blc;
    #pragma unroll
    for (int k4 = 0; k4 < 16; ++k4) {
      float4 x = *(const float4*)&Xa[r * 68 + (k4 << 2)];
      ag = fmaf(x.x, Wc[4*k4+0], ag); ag = fmaf(x.y, Wc[4*k4+1], ag);
      ag = fmaf(x.z, Wc[4*k4+2], ag); ag = fmaf(x.w, Wc[4*k4+3], ag);
    }
    gv[rr] = 1.f / (1.f + __expf(-ag));
  }
  #pragma unroll
  for (int k = 0; k < 64; ++k) Wc[k] = Wo[(k << 6) + c];
  for (int rr = 0; rr < 16; ++rr) {
    int r = (rg << 4) + rr;
    float ao = boc;
    #pragma unroll
    for (int k4 = 0; k4 < 16; ++k4) {
      float4 x = *(const float4*)&Xh[r * 68 + (k4 << 2)];
      ao = fmaf(x.x, Wc[4*k4+0], ao); ao = fmaf(x.y, Wc[4*k4+1], ao);
      ao = fmaf(x.z, Wc[4*k4+2], ao); ao = fmaf(x.w, Wc[4*k4+3], ao);
    }
    float hv = Xh[r * 68 + c];
    float g = gv[rr];
    float val = tanhf(hv) * g + ao * (1.f - g);
    hout[((size_t)(b << 12) + n0 + r) * 64 + c] = val;
    fv[rr] = val;
  }
  __syncthreads();
  #pragma unroll
  for (int rr = 0; rr < 16; ++rr) Xh[((rg << 4) + rr) * 68 + c] = fv[rr];
  __syncthreads();
  int nl = t & 63, dg = t >> 6;
  #pragma unroll
  for (int i = 0; i < 16; ++i) {
    int d = (dg << 4) + i;
    HT[((size_t)((b << 6) + d) << 12) + n0 + nl] = (f16)Xh[nl * 68 + d];
  }
}

// ---------------- layer-1/2 combine (+ optional fused HT write) ----------------
template<int ACT, bool WRT>   // ACT 0: leaky 0.01, 1: relu
__global__ __launch_bounds__(256) void k_comb12(const float* __restrict__ h, const float* __restrict__ adp,
                                                const float* __restrict__ hcur, const float* __restrict__ Wl,
                                                const float* __restrict__ bl, float* __restrict__ hout,
                                                f16* __restrict__ HT) {
  __shared__ float Xa[64 * 68];
  int t = threadIdx.x;
  int b = blockIdx.x >> 6, n0 = (blockIdx.x & 63) << 6;
  #pragma unroll
  for (int i = 0; i < 4; ++i) {
    int idx = t + (i << 8);
    int nl = idx >> 4, d4 = (idx & 15) << 2;
    size_t arow = ((size_t)(n0 + nl) << 10) + (b << 6) + d4;
    float4 s = *(const float4*)&adp[arow];
    #pragma unroll
    for (int p = 1; p < KSPLIT; ++p) {
      float4 q = *(const float4*)&adp[arow + (size_t)p * (4096 * 1024)];
      s.x += q.x; s.y += q.y; s.z += q.z; s.w += q.w;
    }
    *(float4*)&Xa[nl * 68 + d4] = s;
  }
  __syncthreads();
  int c = t & 63, rg = t >> 6;
  float Wc[64];
  #pragma unroll
  for (int k = 0; k < 64; ++k) Wc[k] = Wl[(k << 6) + c];
  float blc = bl[c];
  float fv[16];
  for (int rr = 0; rr < 16; ++rr) {
    int r = (rg << 4) + rr;
    float ag = blc;
    #pragma unroll
    for (int k4 = 0; k4 < 16; ++k4) {
      float4 x = *(const float4*)&Xa[r * 68 + (k4 << 2)];
      ag = fmaf(x.x, Wc[4*k4+0], ag); ag = fmaf(x.y, Wc[4*k4+1], ag);
      ag = fmaf(x.z, Wc[4*k4+2], ag); ag = fmaf(x.w, Wc[4*k4+3], ag);
    }
    float g = 1.f / (1.f + __expf(-ag));
    size_t ridx = ((size_t)(b << 12) + n0 + r) * 64 + c;
    float hv = h[ridx], cv = hcur[ridx];
    float act = ACT ? fmaxf(cv, 0.f) : (cv > 0.f ? cv : 0.01f * cv);
    float val = act * g + hv * (1.f - g);
    hout[ridx] = val;
    fv[rr] = val;
  }
  if (WRT) {
    __syncthreads();
    #pragma unroll
    for (int rr = 0; rr < 16; ++rr) Xa[((rg << 4) + rr) * 68 + c] = fv[rr];
    __syncthreads();
    int nl = t & 63, dg = t >> 6;
    #pragma unroll
    for (int i = 0; i < 16; ++i) {
      int d = (dg << 4) + i;
      HT[((size_t)((b << 6) + d) << 12) + n0 + nl] = (f16)Xa[nl * 68 + d];
    }
  }
}

// ---------------- host launch ----------------
extern "C" void kernel_launch(void* const* d_in, const int* in_sizes, int n_in,
                              void* d_out, int out_size, void* d_ws, size_t ws_size,
                              hipStream_t stream) {
  (void)in_sizes; (void)n_in; (void)out_size; (void)ws_size;
  const float* inp  = (const float*)d_in[0];
  const int*   ei   = (const int*)d_in[1];
  const float* Wseq = (const float*)d_in[2];
  const float* bseq = (const float*)d_in[3];
  const float* SE   = (const float*)d_in[4];
  const float* TE   = (const float*)d_in[5];
  const float* Wg[3]   = {(const float*)d_in[6],  (const float*)d_in[12], (const float*)d_in[18]};
  const float* asrc[3] = {(const float*)d_in[7],  (const float*)d_in[13], (const float*)d_in[19]};
  const float* adst[3] = {(const float*)d_in[8],  (const float*)d_in[14], (const float*)d_in[20]};
  const float* bgp[3]  = {(const float*)d_in[9],  (const float*)d_in[15], (const float*)d_in[21]};
  const float* Wl[3]   = {(const float*)d_in[10], (const float*)d_in[16], (const float*)d_in[22]};
  const float* bl[3]   = {(const float*)d_in[11], (const float*)d_in[17], (const float*)d_in[23]};
  const float* Wo = (const float*)d_in[24];
  const float* bo = (const float*)d_in[25];
  float* out = (float*)d_out;

  uint8_t* ws = (uint8_t*)d_ws;
  size_t o = 0;
  auto nxt = [&](size_t sz) { void* p = ws + o; o += (sz + 255) & ~(size_t)255; return p; };
  f16*   Af   = (f16*)  nxt((size_t)NN * NN * sizeof(f16));        // 32 MB
  f16*   HT   = (f16*)  nxt((size_t)1024 * NN * sizeof(f16));      // 8 MB
  float* h    = (float*)nxt((size_t)ROWS * 64 * 4);                // 16 MB
  float* adp  = (float*)nxt((size_t)KSPLIT * NN * 1024 * 4);       // 64 MB (4 k-split parts)
  f16*   xp   = (f16*)  nxt((size_t)ROWS * 192 * sizeof(f16));     // 24 MB
  float* als  = (float*)nxt((size_t)ROWS * 3 * 4);
  float* ald  = (float*)nxt((size_t)ROWS * 3 * 4);
  float* hcur = (float*)nxt((size_t)ROWS * 64 * 4);                // 16 MB
  float* rowZ = (float*)nxt((size_t)NN * 4);
  float* Zpart= (float*)nxt((size_t)64 * NN * 4);                  // 1 MB
  f16*   SEh  = (f16*)  nxt((size_t)NN * 64 * sizeof(f16));
  f16*   TEh  = (f16*)  nxt((size_t)NN * 64 * sizeof(f16));
  float* va   = (float*)nxt((size_t)3 * 64 * 4);
  float* vd   = (float*)nxt((size_t)3 * 64 * 4);
  int*   cnt  = (int*)  nxt((size_t)NN * 4);
  int*   curp = (int*)  nxt((size_t)NN * 4);
  int*   offs = (int*)  nxt((size_t)NN * 4);
  int*   esrc = (int*)  nxt((size_t)ETOT * 4);

  dim3 blk(256);
  // CSR build
  k_zero<<<16, blk, 0, stream>>>(cnt, NN);
  k_zero<<<16, blk, 0, stream>>>(curp, NN);
  k_count<<<144, blk, 0, stream>>>(ei, cnt);
  k_scan<<<1, blk, 0, stream>>>(cnt, offs);
  k_fill<<<144, blk, 0, stream>>>(ei, offs, curp, esrc);
  // h0 (+HT) + adjacency (MFMA path, raw exp + rowZ)
  k_seq<<<1024, blk, 0, stream>>>(inp, Wseq, bseq, h, HT);
  k_castSE<<<256, blk, 0, stream>>>(SE, SEh);
  k_castTE<<<64, blk, 0, stream>>>(TE, TEh);
  k_adjmm<<<dim3(32, 32), blk, 0, stream>>>(SEh, TEh, Af, Zpart);
  k_rowz<<<16, blk, 0, stream>>>(Zpart, rowZ);
  // ---- layer 0 ----
  k_gemm<<<1024, blk, 0, stream>>>(Af, HT, rowZ, adp);
  k_comb0<<<1024, blk, 0, stream>>>(h, adp, Wl[0], bl[0], Wo, bo, h, HT);
  // ---- layer 1 ----
  k_attv<3><<<1, blk, 0, stream>>>(Wg[1], asrc[1], adst[1], va, vd);
  k_xp<3><<<1024, blk, 0, stream>>>(h, Wg[1], va, vd, xp, als, ald);
  k_gemm<<<1024, blk, 0, stream>>>(Af, HT, rowZ, adp);
  k_agg<3><<<16384, blk, 0, stream>>>(xp, als, ald, offs, cnt, esrc, bgp[1], hcur);
  k_comb12<0, true><<<1024, blk, 0, stream>>>(h, adp, hcur, Wl[1], bl[1], h, HT);
  // ---- layer 2 ----
  k_attv<1><<<1, blk, 0, stream>>>(Wg[2], asrc[2], adst[2], va, vd);
  k_xp<1><<<1024, blk, 0, stream>>>(h, Wg[2], va, vd, xp, als, ald);
  k_gemm<<<1024, blk, 0, stream>>>(Af, HT, rowZ, adp);
  k_agg<1><<<16384, blk, 0, stream>>>(xp, als, ald, offs, cnt, esrc, bgp[2], hcur);
  k_comb12<1, false><<<1024, blk, 0, stream>>>(h, adp, hcur, Wl[2], bl[2], out, (f16*)nullptr);
}

// Round 7
// 435.479 us; speedup vs baseline: 1.2891x; 1.0991x over previous
//
#include <hip/hip_runtime.h>
#include <stdint.h>

// ---- problem constants ----
#define NB 16        // batch
#define NN 4096      // nodes
#define DD 64        // feature dim (== S)
#define EE 32768     // edges (before self loops)
#define ETOT 36864   // edges + self loops
#define ROWS 65536   // B*N
#define KSPLIT 4

typedef _Float16 f16;
typedef f16   half8 __attribute__((ext_vector_type(8)));
typedef f16   f16x8 __attribute__((ext_vector_type(8)));
typedef float f32x4 __attribute__((ext_vector_type(4)));

__device__ __forceinline__ void gload16(const f16* g, f16* l) {
  __builtin_amdgcn_global_load_lds((const __attribute__((address_space(1))) void*)g,
                                   (__attribute__((address_space(3))) void*)l, 16, 0, 0);
}

// ---------------- CSR build ----------------
__global__ __launch_bounds__(256) void k_zero(int* p, int n) {
  int i = blockIdx.x * 256 + threadIdx.x;
  if (i < n) p[i] = 0;
}

__global__ __launch_bounds__(256) void k_count(const int* __restrict__ ei, int* __restrict__ cnt) {
  int t = blockIdx.x * 256 + threadIdx.x;
  if (t >= ETOT) return;
  int d = (t < EE) ? ei[EE + t] : (t - EE);
  atomicAdd(&cnt[d], 1);
}

__global__ __launch_bounds__(256) void k_scan(const int* __restrict__ cnt, int* __restrict__ offs) {
  __shared__ int part[256];
  int t = threadIdx.x;
  int loc[16]; int s = 0;
  #pragma unroll
  for (int i = 0; i < 16; ++i) { int v = cnt[(t << 4) + i]; loc[i] = s; s += v; }
  part[t] = s;
  __syncthreads();
  int own = s;
  for (int d = 1; d < 256; d <<= 1) {
    int u = (t >= d) ? part[t - d] : 0;
    __syncthreads();
    part[t] += u;
    __syncthreads();
  }
  int base = part[t] - own;
  #pragma unroll
  for (int i = 0; i < 16; ++i) offs[(t << 4) + i] = base + loc[i];
}

__global__ __launch_bounds__(256) void k_fill(const int* __restrict__ ei, const int* __restrict__ offs,
                                              int* __restrict__ cur, int* __restrict__ esrc) {
  int t = blockIdx.x * 256 + threadIdx.x;
  if (t >= ETOT) return;
  int s, d;
  if (t < EE) { s = ei[t]; d = ei[EE + t]; } else { s = d = t - EE; }
  int p = atomicAdd(&cur[d], 1);
  esrc[offs[d] + p] = s;
}

// ---------------- seq_linear: h = in^T @ Wseq + b + in^T  (+ fused HT write) ----------------
__global__ __launch_bounds__(256) void k_seq(const float* __restrict__ inp, const float* __restrict__ Wseq,
                                             const float* __restrict__ bseq, float* __restrict__ h,
                                             f16* __restrict__ HT) {
  __shared__ float X[64 * 68];
  int t = threadIdx.x;
  int b = blockIdx.x >> 6, n0 = (blockIdx.x & 63) << 6;
  #pragma unroll
  for (int i = 0; i < 16; ++i) {
    int idx = t + (i << 8);
    int s = idx >> 6, nl = idx & 63;
    X[nl * 68 + s] = inp[((size_t)((b << 6) + s) << 12) + n0 + nl];
  }
  __syncthreads();
  int c = t & 63, rg = t >> 6;
  float Wc[64];
  #pragma unroll
  for (int k = 0; k < 64; ++k) Wc[k] = Wseq[(k << 6) + c];
  float bc = bseq[c];
  float av[16];
  for (int rr = 0; rr < 16; ++rr) {
    int r = (rg << 4) + rr;
    float a = bc + X[r * 68 + c];
    #pragma unroll
    for (int k4 = 0; k4 < 16; ++k4) {
      float4 x = *(const float4*)&X[r * 68 + (k4 << 2)];
      a = fmaf(x.x, Wc[4*k4+0], a); a = fmaf(x.y, Wc[4*k4+1], a);
      a = fmaf(x.z, Wc[4*k4+2], a); a = fmaf(x.w, Wc[4*k4+3], a);
    }
    h[((size_t)(b << 12) + n0 + r) * 64 + c] = a;
    av[rr] = a;
  }
  __syncthreads();
  #pragma unroll
  for (int rr = 0; rr < 16; ++rr) X[((rg << 4) + rr) * 68 + c] = av[rr];
  __syncthreads();
  int nl = t & 63, dg = t >> 6;
  #pragma unroll
  for (int i = 0; i < 16; ++i) {
    int d = (dg << 4) + i;
    HT[((size_t)((b << 6) + d) << 12) + n0 + nl] = (f16)X[nl * 68 + d];
  }
}

// ---------------- adjacency prep: casts ----------------
__global__ __launch_bounds__(256) void k_castSE(const float* __restrict__ SE, f16* __restrict__ SEh) {
  int i = (blockIdx.x * 256 + threadIdx.x) * 4;
  float4 v = *(const float4*)(SE + i);
  f16 o[4] = {(f16)v.x, (f16)v.y, (f16)v.z, (f16)v.w};
  *(uint64_t*)(SEh + i) = *(uint64_t*)o;
}

__global__ __launch_bounds__(256) void k_castTE(const float* __restrict__ TE, f16* __restrict__ TEh) {
  __shared__ float X[64 * 65];
  int t = threadIdx.x;
  int j0 = blockIdx.x << 6;
  #pragma unroll
  for (int i = 0; i < 16; ++i) {
    int idx = t + (i << 8);           // 0..4095 = 64k x 64j
    int k = idx >> 6, jl = idx & 63;
    X[jl * 65 + k] = TE[((size_t)k << 12) + j0 + jl];
  }
  __syncthreads();
  int jl = t >> 2, kg = t & 3;        // 4 threads per output row, 16 k each
  f16 o[16];
  #pragma unroll
  for (int i = 0; i < 16; ++i) o[i] = (f16)X[jl * 65 + (kg << 4) + i];
  f16* dst = TEh + ((size_t)(j0 + jl) << 6) + (kg << 4);
  *(uint64_t*)(dst + 0) = *(uint64_t*)(o + 0);
  *(uint64_t*)(dst + 4) = *(uint64_t*)(o + 4);
  *(uint64_t*)(dst + 8) = *(uint64_t*)(o + 8);
  *(uint64_t*)(dst + 12) = *(uint64_t*)(o + 12);
}

// ---------------- adjacency MFMA GEMM: A = exp(relu(SEh @ TEh^T)) (raw), row partial sums ----------------
__global__ __launch_bounds__(256) void k_adjmm(const f16* __restrict__ SEh, const f16* __restrict__ TEh,
                                               f16* __restrict__ A, float* __restrict__ Zpart) {
  __shared__ f16 Al[128 * 32];
  __shared__ f16 Bl[128 * 32];
  const int t = threadIdx.x, lane = t & 63, w = t >> 6;
  const int m0 = blockIdx.y << 7, j0 = blockIdx.x << 7;
  const int l15 = lane & 15, lhi = lane >> 4;
  const int wm = (w >> 1) << 6, wj = (w & 1) << 6;
  f32x4 acc[4][4] = {};
  const int c0 = (w << 6) + lane;
  const int row0 = c0 >> 2, ko0 = (c0 & 3) << 3;
  const int c1 = c0 + 256;
  const int row1 = c1 >> 2, ko1 = (c1 & 3) << 3;
  const f16* ga0 = SEh + (size_t)(m0 + row0) * 64 + ko0;
  const f16* ga1 = SEh + (size_t)(m0 + row1) * 64 + ko1;
  const f16* gb0 = TEh + (size_t)(j0 + row0) * 64 + ko0;
  const f16* gb1 = TEh + (size_t)(j0 + row1) * 64 + ko1;
  f16* la0 = Al + c0 * 8; f16* la1 = Al + c1 * 8;
  f16* lb0 = Bl + c0 * 8; f16* lb1 = Bl + c1 * 8;
  for (int kt = 0; kt < 2; ++kt) {
    const int kof = kt << 5;
    gload16(ga0 + kof, la0);
    gload16(ga1 + kof, la1);
    gload16(gb0 + kof, lb0);
    gload16(gb1 + kof, lb1);
    __syncthreads();
    half8 af[4], bf[4];
    #pragma unroll
    for (int i = 0; i < 4; ++i) {
      af[i] = *(const half8*)(Al + (wm + i * 16 + l15) * 32 + lhi * 8);
      bf[i] = *(const half8*)(Bl + (wj + i * 16 + l15) * 32 + lhi * 8);
    }
    #pragma unroll
    for (int mi = 0; mi < 4; ++mi)
      #pragma unroll
      for (int nj = 0; nj < 4; ++nj)
        acc[mi][nj] = __builtin_amdgcn_mfma_f32_16x16x32_f16(af[mi], bf[nj], acc[mi][nj], 0, 0, 0);
    __syncthreads();
  }
  float rs[4][4];
  #pragma unroll
  for (int mi = 0; mi < 4; ++mi)
    #pragma unroll
    for (int r = 0; r < 4; ++r) rs[mi][r] = 0.f;
  #pragma unroll
  for (int mi = 0; mi < 4; ++mi)
    #pragma unroll
    for (int nj = 0; nj < 4; ++nj)
      #pragma unroll
      for (int r = 0; r < 4; ++r) {
        int row = m0 + wm + mi * 16 + lhi * 4 + r;
        int col = j0 + wj + nj * 16 + l15;
        float e = __expf(fmaxf(acc[mi][nj][r], 0.f));
        f16 eh = (f16)e;
        A[((size_t)row << 12) + col] = eh;
        rs[mi][r] += (float)eh;      // sum the rounded value for consistency
      }
  #pragma unroll
  for (int mi = 0; mi < 4; ++mi)
    #pragma unroll
    for (int r = 0; r < 4; ++r) {
      float s = rs[mi][r];
      s += __shfl_xor(s, 1); s += __shfl_xor(s, 2);
      s += __shfl_xor(s, 4); s += __shfl_xor(s, 8);
      rs[mi][r] = s;
    }
  if (l15 == 0) {
    int p = (blockIdx.x << 1) + (w & 1);
    #pragma unroll
    for (int mi = 0; mi < 4; ++mi)
      #pragma unroll
      for (int r = 0; r < 4; ++r)
        Zpart[((size_t)p << 12) + m0 + wm + mi * 16 + lhi * 4 + r] = rs[mi][r];
  }
}

__global__ __launch_bounds__(256) void k_rowz(const float* __restrict__ Zpart, float* __restrict__ rowZ) {
  int row = blockIdx.x * 256 + threadIdx.x;
  float s = 0.f;
  #pragma unroll 8
  for (int p = 0; p < 64; ++p) s += Zpart[((size_t)p << 12) + row];
  rowZ[row] = 1.f / s;
}

// ---------------- big GEMM: C[m, j] = rowZ[m] * sum_k Araw[m,k] * BT[j,k] ----------------
// R4 addressing (fastest measured: 52.6 us): [row][32] LDS, 4-lane/row 64B global lines.
// 2-phase double-buffered prefetch, K-split 4, XCD swizzle, rowZ-fused epilogue.
__global__ __launch_bounds__(256) void k_gemm(const f16* __restrict__ A, const f16* __restrict__ BT,
                                              const float* __restrict__ rowZ, float* __restrict__ Cout) {
  __shared__ f16 Al[2][128 * 32];
  __shared__ f16 Bl[2][128 * 32];
  const int t = threadIdx.x, lane = t & 63, w = t >> 6;
  const int wgid = blockIdx.x;
  const int nid = (wgid & 7) * 128 + (wgid >> 3);
  const int z = nid >> 8, rem = nid & 255;
  const int m0 = ((rem >> 3) & 31) << 7, j0 = (rem & 7) << 7;
  const int kbase = z << 10;                       // 1024 K per block
  float* __restrict__ C = Cout + ((size_t)z << 22);
  const int l15 = lane & 15, lhi = lane >> 4;
  const int wm = (w >> 1) << 6, wj = (w & 1) << 6;
  f32x4 acc[4][4] = {};
  const int c0 = (w << 6) + lane;
  const int row0 = c0 >> 2, ko0 = (c0 & 3) << 3;
  const int c1 = c0 + 256;
  const int row1 = c1 >> 2, ko1 = (c1 & 3) << 3;
  const f16* ga0 = A  + (size_t)(m0 + row0) * 4096 + kbase + ko0;
  const f16* ga1 = A  + (size_t)(m0 + row1) * 4096 + kbase + ko1;
  const f16* gb0 = BT + (size_t)(j0 + row0) * 4096 + kbase + ko0;
  const f16* gb1 = BT + (size_t)(j0 + row1) * 4096 + kbase + ko1;

  #define STAGE(buf, kt) do {                         \
    const int kof_ = (kt) << 5;                       \
    gload16(ga0 + kof_, Al[buf] + c0 * 8);            \
    gload16(ga1 + kof_, Al[buf] + c1 * 8);            \
    gload16(gb0 + kof_, Bl[buf] + c0 * 8);            \
    gload16(gb1 + kof_, Bl[buf] + c1 * 8);            \
  } while (0)

  STAGE(0, 0);
  __syncthreads();
  const int NKT = 32;              // 1024 / 32
  for (int kt = 0; kt < NKT; ++kt) {
    const int cur = kt & 1;
    if (kt + 1 < NKT) STAGE(cur ^ 1, kt + 1);
    half8 af[4], bf[4];
    #pragma unroll
    for (int i = 0; i < 4; ++i) {
      af[i] = *(const half8*)(Al[cur] + (wm + i * 16 + l15) * 32 + lhi * 8);
      bf[i] = *(const half8*)(Bl[cur] + (wj + i * 16 + l15) * 32 + lhi * 8);
    }
    #pragma unroll
    for (int mi = 0; mi < 4; ++mi)
      #pragma unroll
      for (int nj = 0; nj < 4; ++nj)
        acc[mi][nj] = __builtin_amdgcn_mfma_f32_16x16x32_f16(af[mi], bf[nj], acc[mi][nj], 0, 0, 0);
    __syncthreads();
  }
  #undef STAGE
  #pragma unroll
  for (int mi = 0; mi < 4; ++mi) {
    float4 z4 = *(const float4*)&rowZ[m0 + wm + mi * 16 + lhi * 4];
    float ziv[4] = {z4.x, z4.y, z4.z, z4.w};
    #pragma unroll
    for (int nj = 0; nj < 4; ++nj)
      #pragma unroll
      for (int r = 0; r < 4; ++r) {
        int row = m0 + wm + mi * 16 + lhi * 4 + r;
        int col = j0 + wj + nj * 16 + l15;
        C[(size_t)row * 1024 + col] = acc[mi][nj][r] * ziv[r];
      }
  }
}

// ---------------- Wgh prep: B^T for xp-GEMM, padded with va/vd columns ----------------
// Wgh[j][k], j<H*64: Wg[k][j]; j=H*64+2h: va[h][k]; j=H*64+2h+1: vd[h][k]; else 0.
template<int H, int NP>
__global__ __launch_bounds__(256) void k_wprep(const float* __restrict__ Wg, const float* __restrict__ asrc,
                                               const float* __restrict__ adst, f16* __restrict__ Wgh) {
  for (int i = blockIdx.x * 256 + threadIdx.x; i < NP * 64; i += 16 * 256) {
    int j = i >> 6, k = i & 63;
    float v;
    if (j < H * 64) {
      v = Wg[(size_t)k * (H * 64) + j];
    } else if (j < H * 64 + 2 * H) {
      int cc = j - H * 64, hh = cc >> 1;
      const float* a = ((cc & 1) ? adst : asrc) + (hh << 6);
      const float* wrow = Wg + (size_t)k * (H * 64) + (hh << 6);
      float s = 0.f;
      #pragma unroll 16
      for (int c = 0; c < 64; ++c) s = fmaf(wrow[c], a[c], s);
      v = s;
    } else v = 0.f;
    Wgh[(size_t)j * 64 + k] = (f16)v;
  }
}

// ---------------- xp = h @ Wg via MFMA (f16 out) + als/ald from padded columns ----------------
// Tile: 128 rows x NP cols; 4 waves: wave w owns rows w*32..w*32+31. K=64 (2 MFMA k-steps).
template<int H, int NP>
__global__ __launch_bounds__(256) void k_xpmm(const float* __restrict__ h, const f16* __restrict__ Wgh,
                                              f16* __restrict__ xp, float* __restrict__ als,
                                              float* __restrict__ ald) {
  __shared__ f16 Ah[128 * 72];
  __shared__ f16 Bh[NP * 72];
  const int t = threadIdx.x, lane = t & 63, w = t >> 6;
  const size_t r0 = (size_t)blockIdx.x * 128;
  // stage A: 128x64 f32 -> f16 (pad stride 72)
  #pragma unroll
  for (int i = 0; i < 8; ++i) {
    int idx = t + (i << 8);
    int row = idx >> 4, k4 = (idx & 15) << 2;
    float4 v = *(const float4*)&h[(r0 + row) * 64 + k4];
    f16 o[4] = {(f16)v.x, (f16)v.y, (f16)v.z, (f16)v.w};
    *(uint64_t*)&Ah[row * 72 + k4] = *(uint64_t*)o;
  }
  // stage B: NPx64 f16
  for (int i = t; i < NP * 16; i += 256) {
    int row = i >> 4, k4 = (i & 15) << 2;
    *(uint64_t*)&Bh[row * 72 + k4] = *(const uint64_t*)&Wgh[(size_t)row * 64 + k4];
  }
  __syncthreads();
  const int l15 = lane & 15, lhi = lane >> 4;
  const int NT = NP / 16;
  f32x4 acc[2][NT] = {};
  #pragma unroll
  for (int kk = 0; kk < 2; ++kk) {
    half8 af[2], bf[NT];
    #pragma unroll
    for (int i = 0; i < 2; ++i)
      af[i] = *(const half8*)&Ah[(w * 32 + i * 16 + l15) * 72 + kk * 32 + lhi * 8];
    #pragma unroll
    for (int j = 0; j < NT; ++j)
      bf[j] = *(const half8*)&Bh[(j * 16 + l15) * 72 + kk * 32 + lhi * 8];
    #pragma unroll
    for (int i = 0; i < 2; ++i)
      #pragma unroll
      for (int j = 0; j < NT; ++j)
        acc[i][j] = __builtin_amdgcn_mfma_f32_16x16x32_f16(af[i], bf[j], acc[i][j], 0, 0, 0);
  }
  #pragma unroll
  for (int i = 0; i < 2; ++i) {
    int rloc = w * 32 + i * 16 + lhi * 4;
    #pragma unroll
    for (int j = 0; j < NT; ++j) {
      #pragma unroll
      for (int r = 0; r < 4; ++r) {
        int col = j * 16 + l15;
        size_t row = r0 + rloc + r;
        float v = acc[i][j][r];
        if (j * 16 + 15 < H * 64) {                  // whole tile inside xp region (compile-time)
          xp[row * (H * 64) + col] = (f16)v;
        } else {
          if (col < H * 64) xp[row * (H * 64) + col] = (f16)v;
          else {
            int cc = col - H * 64;
            if (cc < 2 * H) {
              int hh = cc >> 1;
              if (cc & 1) ald[row * H + hh] = v; else als[row * H + hh] = v;
            }
          }
        }
      }
    }
  }
}

// ---------------- GAT aggregation: one wave per (b, node), lane-parallel softmax ----------------
template<int H>
__global__ __launch_bounds__(256) void k_agg(const f16* __restrict__ xp, const float* __restrict__ als,
                                             const float* __restrict__ ald,
                                             const int* __restrict__ offs, const int* __restrict__ cnt,
                                             const int* __restrict__ esrc, const float* __restrict__ bg,
                                             float* __restrict__ hcur) {
  __shared__ float wbuf[4][H * 64];
  __shared__ int   sbuf[4][64];
  int t = threadIdx.x, lane = t & 63, wv = t >> 6;
  int wid = (blockIdx.x << 2) + wv;
  int b = wid >> 12, n = wid & 4095;
  size_t rbase = (size_t)b << 12;
  int o = offs[n], c = cnt[n];
  float aldh[H], m[H], z[H], acc[H];
  #pragma unroll
  for (int hh = 0; hh < H; ++hh) {
    aldh[hh] = ald[(rbase + n) * H + hh];
    m[hh] = -1e30f; z[hh] = 0.f; acc[hh] = 0.f;
  }
  for (int e0 = 0; e0 < c; e0 += 64) {
    int ce = min(64, c - e0);
    float evl[H]; int sl = 0;
    if (lane < ce) {
      sl = esrc[o + e0 + lane];
      #pragma unroll
      for (int hh = 0; hh < H; ++hh) {
        float ev = als[(rbase + sl) * H + hh] + aldh[hh];
        evl[hh] = ev > 0.f ? ev : 0.2f * ev;
      }
    } else {
      #pragma unroll
      for (int hh = 0; hh < H; ++hh) evl[hh] = -1e30f;
    }
    sbuf[wv][lane] = sl;
    #pragma unroll
    for (int hh = 0; hh < H; ++hh) {
      float v = evl[hh];
      #pragma unroll
      for (int s = 1; s < 64; s <<= 1) v = fmaxf(v, __shfl_xor(v, s));
      float mn = fmaxf(m[hh], v);
      float sc = __expf(m[hh] - mn);
      z[hh] *= sc; acc[hh] *= sc; m[hh] = mn;
      float w = (lane < ce) ? __expf(evl[hh] - mn) : 0.f;
      wbuf[wv][hh * 64 + lane] = w;
      float zs = w;
      #pragma unroll
      for (int s = 1; s < 64; s <<= 1) zs += __shfl_xor(zs, s);
      z[hh] += zs;
    }
    for (int e = 0; e < ce; ++e) {
      int s = sbuf[wv][e];
      const f16* row = xp + (rbase + s) * (size_t)(H * 64) + lane;
      #pragma unroll
      for (int hh = 0; hh < H; ++hh)
        acc[hh] = fmaf(wbuf[wv][hh * 64 + e], (float)row[hh << 6], acc[hh]);
    }
  }
  float r = 0.f;
  #pragma unroll
  for (int hh = 0; hh < H; ++hh) r += acc[hh] / z[hh];
  hcur[(rbase + n) * 64 + lane] = r * (1.f / H) + bg[lane];
}

// ---------------- layer-0 combine (+ fused HT write) ----------------
__global__ __launch_bounds__(256) void k_comb0(const float* __restrict__ h, const float* __restrict__ adp,
                                               const float* __restrict__ Wl, const float* __restrict__ bl,
                                               const float* __restrict__ Wo, const float* __restrict__ bo,
                                               float* __restrict__ hout, f16* __restrict__ HT) {
  __shared__ float Xa[64 * 68];
  __shared__ float Xh[64 * 68];
  int t = threadIdx.x;
  int b = blockIdx.x >> 6, n0 = (blockIdx.x & 63) << 6;
  #pragma unroll
  for (int i = 0; i < 4; ++i) {
    int idx = t + (i << 8);
    int nl = idx >> 4, d4 = (idx & 15) << 2;
    size_t arow = ((size_t)(n0 + nl) << 10) + (b << 6) + d4;
    float4 s = *(const float4*)&adp[arow];
    #pragma unroll
    for (int p = 1; p < KSPLIT; ++p) {
      float4 q = *(const float4*)&adp[arow + (size_t)p * (4096 * 1024)];
      s.x += q.x; s.y += q.y; s.z += q.z; s.w += q.w;
    }
    *(float4*)&Xa[nl * 68 + d4] = s;
    *(float4*)&Xh[nl * 68 + d4] = *(const float4*)&h[((size_t)(b << 12) + n0 + nl) * 64 + d4];
  }
  __syncthreads();
  int c = t & 63, rg = t >> 6;
  float blc = bl[c], boc = bo[c];
  float Wc[64], gv[16], fv[16];
  #pragma unroll
  for (int k = 0; k < 64; ++k) Wc[k] = Wl[(k << 6) + c];
  for (int rr = 0; rr < 16; ++rr) {
    int r = (rg << 4) + rr;
    float ag = blc;
    #pragma unroll
    for (int k4 = 0; k4 < 16; ++k4) {
      float4 x = *(const float4*)&Xa[r * 68 + (k4 << 2)];
      ag = fmaf(x.x, Wc[4*k4+0], ag); ag = fmaf(x.y, Wc[4*k4+1], ag);
      ag = fmaf(x.z, Wc[4*k4+2], ag); ag = fmaf(x.w, Wc[4*k4+3], ag);
    }
    gv[rr] = 1.f / (1.f + __expf(-ag));
  }
  #pragma unroll
  for (int k = 0; k < 64; ++k) Wc[k] = Wo[(k << 6) + c];
  for (int rr = 0; rr < 16; ++rr) {
    int r = (rg << 4) + rr;
    float ao = boc;
    #pragma unroll
    for (int k4 = 0; k4 < 16; ++k4) {
      float4 x = *(const float4*)&Xh[r * 68 + (k4 << 2)];
      ao = fmaf(x.x, Wc[4*k4+0], ao); ao = fmaf(x.y, Wc[4*k4+1], ao);
      ao = fmaf(x.z, Wc[4*k4+2], ao); ao = fmaf(x.w, Wc[4*k4+3], ao);
    }
    float hv = Xh[r * 68 + c];
    float g = gv[rr];
    float val = tanhf(hv) * g + ao * (1.f - g);
    hout[((size_t)(b << 12) + n0 + r) * 64 + c] = val;
    fv[rr] = val;
  }
  __syncthreads();
  #pragma unroll
  for (int rr = 0; rr < 16; ++rr) Xh[((rg << 4) + rr) * 68 + c] = fv[rr];
  __syncthreads();
  int nl = t & 63, dg = t >> 6;
  #pragma unroll
  for (int i = 0; i < 16; ++i) {
    int d = (dg << 4) + i;
    HT[((size_t)((b << 6) + d) << 12) + n0 + nl] = (f16)Xh[nl * 68 + d];
  }
}

// ---------------- layer-1/2 combine (+ optional fused HT write) ----------------
template<int ACT, bool WRT>   // ACT 0: leaky 0.01, 1: relu
__global__ __launch_bounds__(256) void k_comb12(const float* __restrict__ h, const float* __restrict__ adp,
                                                const float* __restrict__ hcur, const float* __restrict__ Wl,
                                                const float* __restrict__ bl, float* __restrict__ hout,
                                                f16* __restrict__ HT) {
  __shared__ float Xa[64 * 68];
  int t = threadIdx.x;
  int b = blockIdx.x >> 6, n0 = (blockIdx.x & 63) << 6;
  #pragma unroll
  for (int i = 0; i < 4; ++i) {
    int idx = t + (i << 8);
    int nl = idx >> 4, d4 = (idx & 15) << 2;
    size_t arow = ((size_t)(n0 + nl) << 10) + (b << 6) + d4;
    float4 s = *(const float4*)&adp[arow];
    #pragma unroll
    for (int p = 1; p < KSPLIT; ++p) {
      float4 q = *(const float4*)&adp[arow + (size_t)p * (4096 * 1024)];
      s.x += q.x; s.y += q.y; s.z += q.z; s.w += q.w;
    }
    *(float4*)&Xa[nl * 68 + d4] = s;
  }
  __syncthreads();
  int c = t & 63, rg = t >> 6;
  float Wc[64];
  #pragma unroll
  for (int k = 0; k < 64; ++k) Wc[k] = Wl[(k << 6) + c];
  float blc = bl[c];
  float fv[16];
  for (int rr = 0; rr < 16; ++rr) {
    int r = (rg << 4) + rr;
    float ag = blc;
    #pragma unroll
    for (int k4 = 0; k4 < 16; ++k4) {
      float4 x = *(const float4*)&Xa[r * 68 + (k4 << 2)];
      ag = fmaf(x.x, Wc[4*k4+0], ag); ag = fmaf(x.y, Wc[4*k4+1], ag);
      ag = fmaf(x.z, Wc[4*k4+2], ag); ag = fmaf(x.w, Wc[4*k4+3], ag);
    }
    float g = 1.f / (1.f + __expf(-ag));
    size_t ridx = ((size_t)(b << 12) + n0 + r) * 64 + c;
    float hv = h[ridx], cv = hcur[ridx];
    float act = ACT ? fmaxf(cv, 0.f) : (cv > 0.f ? cv : 0.01f * cv);
    float val = act * g + hv * (1.f - g);
    hout[ridx] = val;
    fv[rr] = val;
  }
  if (WRT) {
    __syncthreads();
    #pragma unroll
    for (int rr = 0; rr < 16; ++rr) Xa[((rg << 4) + rr) * 68 + c] = fv[rr];
    __syncthreads();
    int nl = t & 63, dg = t >> 6;
    #pragma unroll
    for (int i = 0; i < 16; ++i) {
      int d = (dg << 4) + i;
      HT[((size_t)((b << 6) + d) << 12) + n0 + nl] = (f16)Xa[nl * 68 + d];
    }
  }
}

// ---------------- host launch ----------------
extern "C" void kernel_launch(void* const* d_in, const int* in_sizes, int n_in,
                              void* d_out, int out_size, void* d_ws, size_t ws_size,
                              hipStream_t stream) {
  (void)in_sizes; (void)n_in; (void)out_size; (void)ws_size;
  const float* inp  = (const float*)d_in[0];
  const int*   ei   = (const int*)d_in[1];
  const float* Wseq = (const float*)d_in[2];
  const float* bseq = (const float*)d_in[3];
  const float* SE   = (const float*)d_in[4];
  const float* TE   = (const float*)d_in[5];
  const float* Wg[3]   = {(const float*)d_in[6],  (const float*)d_in[12], (const float*)d_in[18]};
  const float* asrc[3] = {(const float*)d_in[7],  (const float*)d_in[13], (const float*)d_in[19]};
  const float* adst[3] = {(const float*)d_in[8],  (const float*)d_in[14], (const float*)d_in[20]};
  const float* bgp[3]  = {(const float*)d_in[9],  (const float*)d_in[15], (const float*)d_in[21]};
  const float* Wl[3]   = {(const float*)d_in[10], (const float*)d_in[16], (const float*)d_in[22]};
  const float* bl[3]   = {(const float*)d_in[11], (const float*)d_in[17], (const float*)d_in[23]};
  const float* Wo = (const float*)d_in[24];
  const float* bo = (const float*)d_in[25];
  float* out = (float*)d_out;

  uint8_t* ws = (uint8_t*)d_ws;
  size_t o = 0;
  auto nxt = [&](size_t sz) { void* p = ws + o; o += (sz + 255) & ~(size_t)255; return p; };
  f16*   Af   = (f16*)  nxt((size_t)NN * NN * sizeof(f16));        // 32 MB
  f16*   HT   = (f16*)  nxt((size_t)1024 * NN * sizeof(f16));      // 8 MB
  float* h    = (float*)nxt((size_t)ROWS * 64 * 4);                // 16 MB
  float* adp  = (float*)nxt((size_t)KSPLIT * NN * 1024 * 4);       // 64 MB (4 k-split parts)
  f16*   xp   = (f16*)  nxt((size_t)ROWS * 192 * sizeof(f16));     // 24 MB
  float* als  = (float*)nxt((size_t)ROWS * 3 * 4);
  float* ald  = (float*)nxt((size_t)ROWS * 3 * 4);
  float* hcur = (float*)nxt((size_t)ROWS * 64 * 4);                // 16 MB
  float* rowZ = (float*)nxt((size_t)NN * 4);
  float* Zpart= (float*)nxt((size_t)64 * NN * 4);                  // 1 MB
  f16*   SEh  = (f16*)  nxt((size_t)NN * 64 * sizeof(f16));
  f16*   TEh  = (f16*)  nxt((size_t)NN * 64 * sizeof(f16));
  f16*   Wgh  = (f16*)  nxt((size_t)256 * 64 * sizeof(f16));       // padded B^T for xp-GEMM
  int*   cnt  = (int*)  nxt((size_t)NN * 4);
  int*   curp = (int*)  nxt((size_t)NN * 4);
  int*   offs = (int*)  nxt((size_t)NN * 4);
  int*   esrc = (int*)  nxt((size_t)ETOT * 4);

  dim3 blk(256);
  // CSR build
  k_zero<<<16, blk, 0, stream>>>(cnt, NN);
  k_zero<<<16, blk, 0, stream>>>(curp, NN);
  k_count<<<144, blk, 0, stream>>>(ei, cnt);
  k_scan<<<1, blk, 0, stream>>>(cnt, offs);
  k_fill<<<144, blk, 0, stream>>>(ei, offs, curp, esrc);
  // h0 (+HT) + adjacency (MFMA path, raw exp + rowZ)
  k_seq<<<1024, blk, 0, stream>>>(inp, Wseq, bseq, h, HT);
  k_castSE<<<256, blk, 0, stream>>>(SE, SEh);
  k_castTE<<<64, blk, 0, stream>>>(TE, TEh);
  k_adjmm<<<dim3(32, 32), blk, 0, stream>>>(SEh, TEh, Af, Zpart);
  k_rowz<<<16, blk, 0, stream>>>(Zpart, rowZ);
  // ---- layer 0 ----
  k_gemm<<<1024, blk, 0, stream>>>(Af, HT, rowZ, adp);
  k_comb0<<<1024, blk, 0, stream>>>(h, adp, Wl[0], bl[0], Wo, bo, h, HT);
  // ---- layer 1 ----
  k_wprep<3, 208><<<16, blk, 0, stream>>>(Wg[1], asrc[1], adst[1], Wgh);
  k_xpmm<3, 208><<<512, blk, 0, stream>>>(h, Wgh, xp, als, ald);
  k_gemm<<<1024, blk, 0, stream>>>(Af, HT, rowZ, adp);
  k_agg<3><<<16384, blk, 0, stream>>>(xp, als, ald, offs, cnt, esrc, bgp[1], hcur);
  k_comb12<0, true><<<1024, blk, 0, stream>>>(h, adp, hcur, Wl[1], bl[1], h, HT);
  // ---- layer 2 ----
  k_wprep<1, 80><<<16, blk, 0, stream>>>(Wg[2], asrc[2], adst[2], Wgh);
  k_xpmm<1, 80><<<512, blk, 0, stream>>>(h, Wgh, xp, als, ald);
  k_gemm<<<1024, blk, 0, stream>>>(Af, HT, rowZ, adp);
  k_agg<1><<<16384, blk, 0, stream>>>(xp, als, ald, offs, cnt, esrc, bgp[2], hcur);
  k_comb12<1, false><<<1024, blk, 0, stream>>>(h, adp, hcur, Wl[2], bl[2], out, (f16*)nullptr);
}

// Round 8
// 397.182 us; speedup vs baseline: 1.4134x; 1.0964x over previous
//
#include <hip/hip_runtime.h>
#include <stdint.h>

// ---- problem constants ----
#define NB 16        // batch
#define NN 4096      // nodes
#define DD 64        // feature dim (== S)
#define EE 32768     // edges (before self loops)
#define ETOT 36864   // edges + self loops
#define ROWS 65536   // B*N
#define KSPLIT 4

typedef _Float16 f16;
typedef f16   half8 __attribute__((ext_vector_type(8)));
typedef f16   f16x8 __attribute__((ext_vector_type(8)));
typedef f16   f16x4 __attribute__((ext_vector_type(4)));
typedef float f32x4 __attribute__((ext_vector_type(4)));

__device__ __forceinline__ void gload16(const f16* g, f16* l) {
  __builtin_amdgcn_global_load_lds((const __attribute__((address_space(1))) void*)g,
                                   (__attribute__((address_space(3))) void*)l, 16, 0, 0);
}

// ---------------- CSR build ----------------
__global__ __launch_bounds__(256) void k_zero(int* p, int n) {
  int i = blockIdx.x * 256 + threadIdx.x;
  if (i < n) p[i] = 0;
}

__global__ __launch_bounds__(256) void k_count(const int* __restrict__ ei, int* __restrict__ cnt) {
  int t = blockIdx.x * 256 + threadIdx.x;
  if (t >= ETOT) return;
  int d = (t < EE) ? ei[EE + t] : (t - EE);
  atomicAdd(&cnt[d], 1);
}

__global__ __launch_bounds__(256) void k_scan(const int* __restrict__ cnt, int* __restrict__ offs) {
  __shared__ int part[256];
  int t = threadIdx.x;
  int loc[16]; int s = 0;
  #pragma unroll
  for (int i = 0; i < 16; ++i) { int v = cnt[(t << 4) + i]; loc[i] = s; s += v; }
  part[t] = s;
  __syncthreads();
  int own = s;
  for (int d = 1; d < 256; d <<= 1) {
    int u = (t >= d) ? part[t - d] : 0;
    __syncthreads();
    part[t] += u;
    __syncthreads();
  }
  int base = part[t] - own;
  #pragma unroll
  for (int i = 0; i < 16; ++i) offs[(t << 4) + i] = base + loc[i];
}

__global__ __launch_bounds__(256) void k_fill(const int* __restrict__ ei, const int* __restrict__ offs,
                                              int* __restrict__ cur, int* __restrict__ esrc) {
  int t = blockIdx.x * 256 + threadIdx.x;
  if (t >= ETOT) return;
  int s, d;
  if (t < EE) { s = ei[t]; d = ei[EE + t]; } else { s = d = t - EE; }
  int p = atomicAdd(&cur[d], 1);
  esrc[offs[d] + p] = s;
}

// ---------------- seq_linear: h = in^T @ Wseq + b + in^T  (+ fused HT write) ----------------
__global__ __launch_bounds__(256) void k_seq(const float* __restrict__ inp, const float* __restrict__ Wseq,
                                             const float* __restrict__ bseq, float* __restrict__ h,
                                             f16* __restrict__ HT) {
  __shared__ float X[64 * 68];
  int t = threadIdx.x;
  int b = blockIdx.x >> 6, n0 = (blockIdx.x & 63) << 6;
  #pragma unroll
  for (int i = 0; i < 16; ++i) {
    int idx = t + (i << 8);
    int s = idx >> 6, nl = idx & 63;
    X[nl * 68 + s] = inp[((size_t)((b << 6) + s) << 12) + n0 + nl];
  }
  __syncthreads();
  int c = t & 63, rg = t >> 6;
  float Wc[64];
  #pragma unroll
  for (int k = 0; k < 64; ++k) Wc[k] = Wseq[(k << 6) + c];
  float bc = bseq[c];
  float av[16];
  for (int rr = 0; rr < 16; ++rr) {
    int r = (rg << 4) + rr;
    float a = bc + X[r * 68 + c];
    #pragma unroll
    for (int k4 = 0; k4 < 16; ++k4) {
      float4 x = *(const float4*)&X[r * 68 + (k4 << 2)];
      a = fmaf(x.x, Wc[4*k4+0], a); a = fmaf(x.y, Wc[4*k4+1], a);
      a = fmaf(x.z, Wc[4*k4+2], a); a = fmaf(x.w, Wc[4*k4+3], a);
    }
    h[((size_t)(b << 12) + n0 + r) * 64 + c] = a;
    av[rr] = a;
  }
  __syncthreads();
  #pragma unroll
  for (int rr = 0; rr < 16; ++rr) X[((rg << 4) + rr) * 68 + c] = av[rr];
  __syncthreads();
  int nl = t & 63, dg = t >> 6;
  #pragma unroll
  for (int i = 0; i < 16; ++i) {
    int d = (dg << 4) + i;
    HT[((size_t)((b << 6) + d) << 12) + n0 + nl] = (f16)X[nl * 68 + d];
  }
}

// ---------------- adjacency prep: casts ----------------
__global__ __launch_bounds__(256) void k_castSE(const float* __restrict__ SE, f16* __restrict__ SEh) {
  int i = (blockIdx.x * 256 + threadIdx.x) * 4;
  float4 v = *(const float4*)(SE + i);
  f16 o[4] = {(f16)v.x, (f16)v.y, (f16)v.z, (f16)v.w};
  *(uint64_t*)(SEh + i) = *(uint64_t*)o;
}

__global__ __launch_bounds__(256) void k_castTE(const float* __restrict__ TE, f16* __restrict__ TEh) {
  __shared__ float X[64 * 65];
  int t = threadIdx.x;
  int j0 = blockIdx.x << 6;
  #pragma unroll
  for (int i = 0; i < 16; ++i) {
    int idx = t + (i << 8);           // 0..4095 = 64k x 64j
    int k = idx >> 6, jl = idx & 63;
    X[jl * 65 + k] = TE[((size_t)k << 12) + j0 + jl];
  }
  __syncthreads();
  int jl = t >> 2, kg = t & 3;        // 4 threads per output row, 16 k each
  f16 o[16];
  #pragma unroll
  for (int i = 0; i < 16; ++i) o[i] = (f16)X[jl * 65 + (kg << 4) + i];
  f16* dst = TEh + ((size_t)(j0 + jl) << 6) + (kg << 4);
  *(uint64_t*)(dst + 0) = *(uint64_t*)(o + 0);
  *(uint64_t*)(dst + 4) = *(uint64_t*)(o + 4);
  *(uint64_t*)(dst + 8) = *(uint64_t*)(o + 8);
  *(uint64_t*)(dst + 12) = *(uint64_t*)(o + 12);
}

// ---------------- adjacency MFMA GEMM: A = exp(relu(SEh @ TEh^T)) (raw), row partial sums ----------------
__global__ __launch_bounds__(256) void k_adjmm(const f16* __restrict__ SEh, const f16* __restrict__ TEh,
                                               f16* __restrict__ A, float* __restrict__ Zpart) {
  __shared__ f16 Al[128 * 32];
  __shared__ f16 Bl[128 * 32];
  const int t = threadIdx.x, lane = t & 63, w = t >> 6;
  const int m0 = blockIdx.y << 7, j0 = blockIdx.x << 7;
  const int l15 = lane & 15, lhi = lane >> 4;
  const int wm = (w >> 1) << 6, wj = (w & 1) << 6;
  f32x4 acc[4][4] = {};
  const int c0 = (w << 6) + lane;
  const int row0 = c0 >> 2, ko0 = (c0 & 3) << 3;
  const int c1 = c0 + 256;
  const int row1 = c1 >> 2, ko1 = (c1 & 3) << 3;
  const f16* ga0 = SEh + (size_t)(m0 + row0) * 64 + ko0;
  const f16* ga1 = SEh + (size_t)(m0 + row1) * 64 + ko1;
  const f16* gb0 = TEh + (size_t)(j0 + row0) * 64 + ko0;
  const f16* gb1 = TEh + (size_t)(j0 + row1) * 64 + ko1;
  f16* la0 = Al + c0 * 8; f16* la1 = Al + c1 * 8;
  f16* lb0 = Bl + c0 * 8; f16* lb1 = Bl + c1 * 8;
  for (int kt = 0; kt < 2; ++kt) {
    const int kof = kt << 5;
    gload16(ga0 + kof, la0);
    gload16(ga1 + kof, la1);
    gload16(gb0 + kof, lb0);
    gload16(gb1 + kof, lb1);
    __syncthreads();
    half8 af[4], bf[4];
    #pragma unroll
    for (int i = 0; i < 4; ++i) {
      af[i] = *(const half8*)(Al + (wm + i * 16 + l15) * 32 + lhi * 8);
      bf[i] = *(const half8*)(Bl + (wj + i * 16 + l15) * 32 + lhi * 8);
    }
    #pragma unroll
    for (int mi = 0; mi < 4; ++mi)
      #pragma unroll
      for (int nj = 0; nj < 4; ++nj)
        acc[mi][nj] = __builtin_amdgcn_mfma_f32_16x16x32_f16(af[mi], bf[nj], acc[mi][nj], 0, 0, 0);
    __syncthreads();
  }
  float rs[4][4];
  #pragma unroll
  for (int mi = 0; mi < 4; ++mi)
    #pragma unroll
    for (int r = 0; r < 4; ++r) rs[mi][r] = 0.f;
  #pragma unroll
  for (int mi = 0; mi < 4; ++mi)
    #pragma unroll
    for (int nj = 0; nj < 4; ++nj)
      #pragma unroll
      for (int r = 0; r < 4; ++r) {
        int row = m0 + wm + mi * 16 + lhi * 4 + r;
        int col = j0 + wj + nj * 16 + l15;
        float e = __expf(fmaxf(acc[mi][nj][r], 0.f));
        f16 eh = (f16)e;
        A[((size_t)row << 12) + col] = eh;
        rs[mi][r] += (float)eh;      // sum the rounded value for consistency
      }
  #pragma unroll
  for (int mi = 0; mi < 4; ++mi)
    #pragma unroll
    for (int r = 0; r < 4; ++r) {
      float s = rs[mi][r];
      s += __shfl_xor(s, 1); s += __shfl_xor(s, 2);
      s += __shfl_xor(s, 4); s += __shfl_xor(s, 8);
      rs[mi][r] = s;
    }
  if (l15 == 0) {
    int p = (blockIdx.x << 1) + (w & 1);
    #pragma unroll
    for (int mi = 0; mi < 4; ++mi)
      #pragma unroll
      for (int r = 0; r < 4; ++r)
        Zpart[((size_t)p << 12) + m0 + wm + mi * 16 + lhi * 4 + r] = rs[mi][r];
  }
}

__global__ __launch_bounds__(256) void k_rowz(const float* __restrict__ Zpart, float* __restrict__ rowZ) {
  int row = blockIdx.x * 256 + threadIdx.x;
  float s = 0.f;
  #pragma unroll 8
  for (int p = 0; p < 64; ++p) s += Zpart[((size_t)p << 12) + row];
  rowZ[row] = 1.f / s;
}

// ---------------- big GEMM: Cpart[m, j] = sum_k Araw[m,k] * BT[j,k]  (f16 partials) ----------------
// R4 addressing exactly (64-VGPR epilogue, no rowZ here -- normalization moved to combine).
// 2-phase double-buffered prefetch, K-split 4, XCD swizzle.
__global__ __launch_bounds__(256) void k_gemm(const f16* __restrict__ A, const f16* __restrict__ BT,
                                              f16* __restrict__ Cout) {
  __shared__ f16 Al[2][128 * 32];
  __shared__ f16 Bl[2][128 * 32];
  const int t = threadIdx.x, lane = t & 63, w = t >> 6;
  const int wgid = blockIdx.x;
  const int nid = (wgid & 7) * 128 + (wgid >> 3);
  const int z = nid >> 8, rem = nid & 255;
  const int m0 = ((rem >> 3) & 31) << 7, j0 = (rem & 7) << 7;
  const int kbase = z << 10;                       // 1024 K per block
  f16* __restrict__ C = Cout + ((size_t)z << 22);
  const int l15 = lane & 15, lhi = lane >> 4;
  const int wm = (w >> 1) << 6, wj = (w & 1) << 6;
  f32x4 acc[4][4] = {};
  const int c0 = (w << 6) + lane;
  const int row0 = c0 >> 2, ko0 = (c0 & 3) << 3;
  const int c1 = c0 + 256;
  const int row1 = c1 >> 2, ko1 = (c1 & 3) << 3;
  const f16* ga0 = A  + (size_t)(m0 + row0) * 4096 + kbase + ko0;
  const f16* ga1 = A  + (size_t)(m0 + row1) * 4096 + kbase + ko1;
  const f16* gb0 = BT + (size_t)(j0 + row0) * 4096 + kbase + ko0;
  const f16* gb1 = BT + (size_t)(j0 + row1) * 4096 + kbase + ko1;

  #define STAGE(buf, kt) do {                         \
    const int kof_ = (kt) << 5;                       \
    gload16(ga0 + kof_, Al[buf] + c0 * 8);            \
    gload16(ga1 + kof_, Al[buf] + c1 * 8);            \
    gload16(gb0 + kof_, Bl[buf] + c0 * 8);            \
    gload16(gb1 + kof_, Bl[buf] + c1 * 8);            \
  } while (0)

  STAGE(0, 0);
  __syncthreads();
  const int NKT = 32;              // 1024 / 32
  for (int kt = 0; kt < NKT; ++kt) {
    const int cur = kt & 1;
    if (kt + 1 < NKT) STAGE(cur ^ 1, kt + 1);
    half8 af[4], bf[4];
    #pragma unroll
    for (int i = 0; i < 4; ++i) {
      af[i] = *(const half8*)(Al[cur] + (wm + i * 16 + l15) * 32 + lhi * 8);
      bf[i] = *(const half8*)(Bl[cur] + (wj + i * 16 + l15) * 32 + lhi * 8);
    }
    #pragma unroll
    for (int mi = 0; mi < 4; ++mi)
      #pragma unroll
      for (int nj = 0; nj < 4; ++nj)
        acc[mi][nj] = __builtin_amdgcn_mfma_f32_16x16x32_f16(af[mi], bf[nj], acc[mi][nj], 0, 0, 0);
    __syncthreads();
  }
  #undef STAGE
  #pragma unroll
  for (int mi = 0; mi < 4; ++mi)
    #pragma unroll
    for (int nj = 0; nj < 4; ++nj)
      #pragma unroll
      for (int r = 0; r < 4; ++r) {
        int row = m0 + wm + mi * 16 + lhi * 4 + r;
        int col = j0 + wj + nj * 16 + l15;
        C[(size_t)row * 1024 + col] = (f16)acc[mi][nj][r];
      }
}

// ---------------- Wgh prep: B^T for xp-GEMM, padded with va/vd columns ----------------
template<int H, int NP>
__global__ __launch_bounds__(256) void k_wprep(const float* __restrict__ Wg, const float* __restrict__ asrc,
                                               const float* __restrict__ adst, f16* __restrict__ Wgh) {
  for (int i = blockIdx.x * 256 + threadIdx.x; i < NP * 64; i += 16 * 256) {
    int j = i >> 6, k = i & 63;
    float v;
    if (j < H * 64) {
      v = Wg[(size_t)k * (H * 64) + j];
    } else if (j < H * 64 + 2 * H) {
      int cc = j - H * 64, hh = cc >> 1;
      const float* a = ((cc & 1) ? adst : asrc) + (hh << 6);
      const float* wrow = Wg + (size_t)k * (H * 64) + (hh << 6);
      float s = 0.f;
      #pragma unroll 16
      for (int c = 0; c < 64; ++c) s = fmaf(wrow[c], a[c], s);
      v = s;
    } else v = 0.f;
    Wgh[(size_t)j * 64 + k] = (f16)v;
  }
}

// ---------------- xp = h @ Wg via MFMA (f16 out) + als/ald from padded columns ----------------
template<int H, int NP>
__global__ __launch_bounds__(256) void k_xpmm(const float* __restrict__ h, const f16* __restrict__ Wgh,
                                              f16* __restrict__ xp, float* __restrict__ als,
                                              float* __restrict__ ald) {
  __shared__ f16 Ah[128 * 72];
  __shared__ f16 Bh[NP * 72];
  const int t = threadIdx.x, lane = t & 63, w = t >> 6;
  const size_t r0 = (size_t)blockIdx.x * 128;
  #pragma unroll
  for (int i = 0; i < 8; ++i) {
    int idx = t + (i << 8);
    int row = idx >> 4, k4 = (idx & 15) << 2;
    float4 v = *(const float4*)&h[(r0 + row) * 64 + k4];
    f16 o[4] = {(f16)v.x, (f16)v.y, (f16)v.z, (f16)v.w};
    *(uint64_t*)&Ah[row * 72 + k4] = *(uint64_t*)o;
  }
  for (int i = t; i < NP * 16; i += 256) {
    int row = i >> 4, k4 = (i & 15) << 2;
    *(uint64_t*)&Bh[row * 72 + k4] = *(const uint64_t*)&Wgh[(size_t)row * 64 + k4];
  }
  __syncthreads();
  const int l15 = lane & 15, lhi = lane >> 4;
  const int NT = NP / 16;
  f32x4 acc[2][NT] = {};
  #pragma unroll
  for (int kk = 0; kk < 2; ++kk) {
    half8 af[2], bf[NT];
    #pragma unroll
    for (int i = 0; i < 2; ++i)
      af[i] = *(const half8*)&Ah[(w * 32 + i * 16 + l15) * 72 + kk * 32 + lhi * 8];
    #pragma unroll
    for (int j = 0; j < NT; ++j)
      bf[j] = *(const half8*)&Bh[(j * 16 + l15) * 72 + kk * 32 + lhi * 8];
    #pragma unroll
    for (int i = 0; i < 2; ++i)
      #pragma unroll
      for (int j = 0; j < NT; ++j)
        acc[i][j] = __builtin_amdgcn_mfma_f32_16x16x32_f16(af[i], bf[j], acc[i][j], 0, 0, 0);
  }
  #pragma unroll
  for (int i = 0; i < 2; ++i) {
    int rloc = w * 32 + i * 16 + lhi * 4;
    #pragma unroll
    for (int j = 0; j < NT; ++j) {
      #pragma unroll
      for (int r = 0; r < 4; ++r) {
        int col = j * 16 + l15;
        size_t row = r0 + rloc + r;
        float v = acc[i][j][r];
        if (j * 16 + 15 < H * 64) {
          xp[row * (H * 64) + col] = (f16)v;
        } else {
          if (col < H * 64) xp[row * (H * 64) + col] = (f16)v;
          else {
            int cc = col - H * 64;
            if (cc < 2 * H) {
              int hh = cc >> 1;
              if (cc & 1) ald[row * H + hh] = v; else als[row * H + hh] = v;
            }
          }
        }
      }
    }
  }
}

// ---------------- GAT aggregation: one wave per (b, node), lane-parallel softmax ----------------
template<int H>
__global__ __launch_bounds__(256) void k_agg(const f16* __restrict__ xp, const float* __restrict__ als,
                                             const float* __restrict__ ald,
                                             const int* __restrict__ offs, const int* __restrict__ cnt,
                                             const int* __restrict__ esrc, const float* __restrict__ bg,
                                             float* __restrict__ hcur) {
  __shared__ float wbuf[4][H * 64];
  __shared__ int   sbuf[4][64];
  int t = threadIdx.x, lane = t & 63, wv = t >> 6;
  int wid = (blockIdx.x << 2) + wv;
  int b = wid >> 12, n = wid & 4095;
  size_t rbase = (size_t)b << 12;
  int o = offs[n], c = cnt[n];
  float aldh[H], m[H], z[H], acc[H];
  #pragma unroll
  for (int hh = 0; hh < H; ++hh) {
    aldh[hh] = ald[(rbase + n) * H + hh];
    m[hh] = -1e30f; z[hh] = 0.f; acc[hh] = 0.f;
  }
  for (int e0 = 0; e0 < c; e0 += 64) {
    int ce = min(64, c - e0);
    float evl[H]; int sl = 0;
    if (lane < ce) {
      sl = esrc[o + e0 + lane];
      #pragma unroll
      for (int hh = 0; hh < H; ++hh) {
        float ev = als[(rbase + sl) * H + hh] + aldh[hh];
        evl[hh] = ev > 0.f ? ev : 0.2f * ev;
      }
    } else {
      #pragma unroll
      for (int hh = 0; hh < H; ++hh) evl[hh] = -1e30f;
    }
    sbuf[wv][lane] = sl;
    #pragma unroll
    for (int hh = 0; hh < H; ++hh) {
      float v = evl[hh];
      #pragma unroll
      for (int s = 1; s < 64; s <<= 1) v = fmaxf(v, __shfl_xor(v, s));
      float mn = fmaxf(m[hh], v);
      float sc = __expf(m[hh] - mn);
      z[hh] *= sc; acc[hh] *= sc; m[hh] = mn;
      float w = (lane < ce) ? __expf(evl[hh] - mn) : 0.f;
      wbuf[wv][hh * 64 + lane] = w;
      float zs = w;
      #pragma unroll
      for (int s = 1; s < 64; s <<= 1) zs += __shfl_xor(zs, s);
      z[hh] += zs;
    }
    for (int e = 0; e < ce; ++e) {
      int s = sbuf[wv][e];
      const f16* row = xp + (rbase + s) * (size_t)(H * 64) + lane;
      #pragma unroll
      for (int hh = 0; hh < H; ++hh)
        acc[hh] = fmaf(wbuf[wv][hh * 64 + e], (float)row[hh << 6], acc[hh]);
    }
  }
  float r = 0.f;
  #pragma unroll
  for (int hh = 0; hh < H; ++hh) r += acc[hh] / z[hh];
  hcur[(rbase + n) * 64 + lane] = r * (1.f / H) + bg[lane];
}

// ---------------- layer-0 combine (+ fused HT write); adp f16 partials * rowZ ----------------
__global__ __launch_bounds__(256) void k_comb0(const float* __restrict__ h, const f16* __restrict__ adp,
                                               const float* __restrict__ rowZ,
                                               const float* __restrict__ Wl, const float* __restrict__ bl,
                                               const float* __restrict__ Wo, const float* __restrict__ bo,
                                               float* __restrict__ hout, f16* __restrict__ HT) {
  __shared__ float Xa[64 * 68];
  __shared__ float Xh[64 * 68];
  int t = threadIdx.x;
  int b = blockIdx.x >> 6, n0 = (blockIdx.x & 63) << 6;
  #pragma unroll
  for (int i = 0; i < 4; ++i) {
    int idx = t + (i << 8);
    int nl = idx >> 4, d4 = (idx & 15) << 2;
    size_t arow = ((size_t)(n0 + nl) << 10) + (b << 6) + d4;
    float zi = rowZ[n0 + nl];
    float4 s = {0.f, 0.f, 0.f, 0.f};
    #pragma unroll
    for (int p = 0; p < KSPLIT; ++p) {
      f16x4 q = *(const f16x4*)&adp[arow + (size_t)p * (4096 * 1024)];
      s.x += (float)q[0]; s.y += (float)q[1]; s.z += (float)q[2]; s.w += (float)q[3];
    }
    s.x *= zi; s.y *= zi; s.z *= zi; s.w *= zi;
    *(float4*)&Xa[nl * 68 + d4] = s;
    *(float4*)&Xh[nl * 68 + d4] = *(const float4*)&h[((size_t)(b << 12) + n0 + nl) * 64 + d4];
  }
  __syncthreads();
  int c = t & 63, rg = t >> 6;
  float blc = bl[c], boc = bo[c];
  float Wc[64], gv[16], fv[16];
  #pragma unroll
  for (int k = 0; k < 64; ++k) Wc[k] = Wl[(k << 6) + c];
  for (int rr = 0; rr < 16; ++rr) {
    int r = (rg << 4) + rr;
    float ag = blc;
    #pragma unroll
    for (int k4 = 0; k4 < 16; ++k4) {
      float4 x = *(const float4*)&Xa[r * 68 + (k4 << 2)];
      ag = fmaf(x.x, Wc[4*k4+0], ag); ag = fmaf(x.y, Wc[4*k4+1], ag);
      ag = fmaf(x.z, Wc[4*k4+2], ag); ag = fmaf(x.w, Wc[4*k4+3], ag);
    }
    gv[rr] = 1.f / (1.f + __expf(-ag));
  }
  #pragma unroll
  for (int k = 0; k < 64; ++k) Wc[k] = Wo[(k << 6) + c];
  for (int rr = 0; rr < 16; ++rr) {
    int r = (rg << 4) + rr;
    float ao = boc;
    #pragma unroll
    for (int k4 = 0; k4 < 16; ++k4) {
      float4 x = *(const float4*)&Xh[r * 68 + (k4 << 2)];
      ao = fmaf(x.x, Wc[4*k4+0], ao); ao = fmaf(x.y, Wc[4*k4+1], ao);
      ao = fmaf(x.z, Wc[4*k4+2], ao); ao = fmaf(x.w, Wc[4*k4+3], ao);
    }
    float hv = Xh[r * 68 + c];
    float g = gv[rr];
    float val = tanhf(hv) * g + ao * (1.f - g);
    hout[((size_t)(b << 12) + n0 + r) * 64 + c] = val;
    fv[rr] = val;
  }
  __syncthreads();
  #pragma unroll
  for (int rr = 0; rr < 16; ++rr) Xh[((rg << 4) + rr) * 68 + c] = fv[rr];
  __syncthreads();
  int nl = t & 63, dg = t >> 6;
  #pragma unroll
  for (int i = 0; i < 16; ++i) {
    int d = (dg << 4) + i;
    HT[((size_t)((b << 6) + d) << 12) + n0 + nl] = (f16)Xh[nl * 68 + d];
  }
}

// ---------------- layer-1/2 combine (+ optional fused HT write); adp f16 partials * rowZ ----------------
template<int ACT, bool WRT>   // ACT 0: leaky 0.01, 1: relu
__global__ __launch_bounds__(256) void k_comb12(const float* __restrict__ h, const f16* __restrict__ adp,
                                                const float* __restrict__ rowZ,
                                                const float* __restrict__ hcur, const float* __restrict__ Wl,
                                                const float* __restrict__ bl, float* __restrict__ hout,
                                                f16* __restrict__ HT) {
  __shared__ float Xa[64 * 68];
  int t = threadIdx.x;
  int b = blockIdx.x >> 6, n0 = (blockIdx.x & 63) << 6;
  #pragma unroll
  for (int i = 0; i < 4; ++i) {
    int idx = t + (i << 8);
    int nl = idx >> 4, d4 = (idx & 15) << 2;
    size_t arow = ((size_t)(n0 + nl) << 10) + (b << 6) + d4;
    float zi = rowZ[n0 + nl];
    float4 s = {0.f, 0.f, 0.f, 0.f};
    #pragma unroll
    for (int p = 0; p < KSPLIT; ++p) {
      f16x4 q = *(const f16x4*)&adp[arow + (size_t)p * (4096 * 1024)];
      s.x += (float)q[0]; s.y += (float)q[1]; s.z += (float)q[2]; s.w += (float)q[3];
    }
    s.x *= zi; s.y *= zi; s.z *= zi; s.w *= zi;
    *(float4*)&Xa[nl * 68 + d4] = s;
  }
  __syncthreads();
  int c = t & 63, rg = t >> 6;
  float Wc[64];
  #pragma unroll
  for (int k = 0; k < 64; ++k) Wc[k] = Wl[(k << 6) + c];
  float blc = bl[c];
  float fv[16];
  for (int rr = 0; rr < 16; ++rr) {
    int r = (rg << 4) + rr;
    float ag = blc;
    #pragma unroll
    for (int k4 = 0; k4 < 16; ++k4) {
      float4 x = *(const float4*)&Xa[r * 68 + (k4 << 2)];
      ag = fmaf(x.x, Wc[4*k4+0], ag); ag = fmaf(x.y, Wc[4*k4+1], ag);
      ag = fmaf(x.z, Wc[4*k4+2], ag); ag = fmaf(x.w, Wc[4*k4+3], ag);
    }
    float g = 1.f / (1.f + __expf(-ag));
    size_t ridx = ((size_t)(b << 12) + n0 + r) * 64 + c;
    float hv = h[ridx], cv = hcur[ridx];
    float act = ACT ? fmaxf(cv, 0.f) : (cv > 0.f ? cv : 0.01f * cv);
    float val = act * g + hv * (1.f - g);
    hout[ridx] = val;
    fv[rr] = val;
  }
  if (WRT) {
    __syncthreads();
    #pragma unroll
    for (int rr = 0; rr < 16; ++rr) Xa[((rg << 4) + rr) * 68 + c] = fv[rr];
    __syncthreads();
    int nl = t & 63, dg = t >> 6;
    #pragma unroll
    for (int i = 0; i < 16; ++i) {
      int d = (dg << 4) + i;
      HT[((size_t)((b << 6) + d) << 12) + n0 + nl] = (f16)Xa[nl * 68 + d];
    }
  }
}

// ---------------- host launch ----------------
extern "C" void kernel_launch(void* const* d_in, const int* in_sizes, int n_in,
                              void* d_out, int out_size, void* d_ws, size_t ws_size,
                              hipStream_t stream) {
  (void)in_sizes; (void)n_in; (void)out_size; (void)ws_size;
  const float* inp  = (const float*)d_in[0];
  const int*   ei   = (const int*)d_in[1];
  const float* Wseq = (const float*)d_in[2];
  const float* bseq = (const float*)d_in[3];
  const float* SE   = (const float*)d_in[4];
  const float* TE   = (const float*)d_in[5];
  const float* Wg[3]   = {(const float*)d_in[6],  (const float*)d_in[12], (const float*)d_in[18]};
  const float* asrc[3] = {(const float*)d_in[7],  (const float*)d_in[13], (const float*)d_in[19]};
  const float* adst[3] = {(const float*)d_in[8],  (const float*)d_in[14], (const float*)d_in[20]};
  const float* bgp[3]  = {(const float*)d_in[9],  (const float*)d_in[15], (const float*)d_in[21]};
  const float* Wl[3]   = {(const float*)d_in[10], (const float*)d_in[16], (const float*)d_in[22]};
  const float* bl[3]   = {(const float*)d_in[11], (const float*)d_in[17], (const float*)d_in[23]};
  const float* Wo = (const float*)d_in[24];
  const float* bo = (const float*)d_in[25];
  float* out = (float*)d_out;

  uint8_t* ws = (uint8_t*)d_ws;
  size_t o = 0;
  auto nxt = [&](size_t sz) { void* p = ws + o; o += (sz + 255) & ~(size_t)255; return p; };
  f16*   Af   = (f16*)  nxt((size_t)NN * NN * sizeof(f16));        // 32 MB
  f16*   HT   = (f16*)  nxt((size_t)1024 * NN * sizeof(f16));      // 8 MB
  float* h    = (float*)nxt((size_t)ROWS * 64 * 4);                // 16 MB
  f16*   adp  = (f16*)  nxt((size_t)KSPLIT * NN * 1024 * sizeof(f16)); // 32 MB (4 f16 k-split parts)
  f16*   xp   = (f16*)  nxt((size_t)ROWS * 192 * sizeof(f16));     // 24 MB
  float* als  = (float*)nxt((size_t)ROWS * 3 * 4);
  float* ald  = (float*)nxt((size_t)ROWS * 3 * 4);
  float* hcur = (float*)nxt((size_t)ROWS * 64 * 4);                // 16 MB
  float* rowZ = (float*)nxt((size_t)NN * 4);
  float* Zpart= (float*)nxt((size_t)64 * NN * 4);                  // 1 MB
  f16*   SEh  = (f16*)  nxt((size_t)NN * 64 * sizeof(f16));
  f16*   TEh  = (f16*)  nxt((size_t)NN * 64 * sizeof(f16));
  f16*   Wgh  = (f16*)  nxt((size_t)256 * 64 * sizeof(f16));       // padded B^T for xp-GEMM
  int*   cnt  = (int*)  nxt((size_t)NN * 4);
  int*   curp = (int*)  nxt((size_t)NN * 4);
  int*   offs = (int*)  nxt((size_t)NN * 4);
  int*   esrc = (int*)  nxt((size_t)ETOT * 4);

  dim3 blk(256);
  // CSR build
  k_zero<<<16, blk, 0, stream>>>(cnt, NN);
  k_zero<<<16, blk, 0, stream>>>(curp, NN);
  k_count<<<144, blk, 0, stream>>>(ei, cnt);
  k_scan<<<1, blk, 0, stream>>>(cnt, offs);
  k_fill<<<144, blk, 0, stream>>>(ei, offs, curp, esrc);
  // h0 (+HT) + adjacency (MFMA path, raw exp + rowZ)
  k_seq<<<1024, blk, 0, stream>>>(inp, Wseq, bseq, h, HT);
  k_castSE<<<256, blk, 0, stream>>>(SE, SEh);
  k_castTE<<<64, blk, 0, stream>>>(TE, TEh);
  k_adjmm<<<dim3(32, 32), blk, 0, stream>>>(SEh, TEh, Af, Zpart);
  k_rowz<<<16, blk, 0, stream>>>(Zpart, rowZ);
  // ---- layer 0 ----
  k_gemm<<<1024, blk, 0, stream>>>(Af, HT, adp);
  k_comb0<<<1024, blk, 0, stream>>>(h, adp, rowZ, Wl[0], bl[0], Wo, bo, h, HT);
  // ---- layer 1 ----
  k_wprep<3, 208><<<16, blk, 0, stream>>>(Wg[1], asrc[1], adst[1], Wgh);
  k_xpmm<3, 208><<<512, blk, 0, stream>>>(h, Wgh, xp, als, ald);
  k_gemm<<<1024, blk, 0, stream>>>(Af, HT, adp);
  k_agg<3><<<16384, blk, 0, stream>>>(xp, als, ald, offs, cnt, esrc, bgp[1], hcur);
  k_comb12<0, true><<<1024, blk, 0, stream>>>(h, adp, rowZ, hcur, Wl[1], bl[1], h, HT);
  // ---- layer 2 ----
  k_wprep<1, 80><<<16, blk, 0, stream>>>(Wg[2], asrc[2], adst[2], Wgh);
  k_xpmm<1, 80><<<512, blk, 0, stream>>>(h, Wgh, xp, als, ald);
  k_gemm<<<1024, blk, 0, stream>>>(Af, HT, adp);
  k_agg<1><<<16384, blk, 0, stream>>>(xp, als, ald, offs, cnt, esrc, bgp[2], hcur);
  k_comb12<1, false><<<1024, blk, 0, stream>>>(h, adp, rowZ, hcur, Wl[2], bl[2], out, (f16*)nullptr);
}

// Round 9
// 355.986 us; speedup vs baseline: 1.5770x; 1.1157x over previous
//
#include <hip/hip_runtime.h>
#include <stdint.h>

// ---- problem constants ----
#define NB 16        // batch
#define NN 4096      // nodes
#define DD 64        // feature dim (== S)
#define EE 32768     // edges (before self loops)
#define ETOT 36864   // edges + self loops
#define ROWS 65536   // B*N
#define KSPLIT 2

typedef _Float16 f16;
typedef f16   half8 __attribute__((ext_vector_type(8)));
typedef f16   f16x8 __attribute__((ext_vector_type(8)));
typedef f16   f16x4 __attribute__((ext_vector_type(4)));
typedef float f32x4 __attribute__((ext_vector_type(4)));

__device__ __forceinline__ void gload16(const f16* g, f16* l) {
  __builtin_amdgcn_global_load_lds((const __attribute__((address_space(1))) void*)g,
                                   (__attribute__((address_space(3))) void*)l, 16, 0, 0);
}

// ---------------- CSR build ----------------
__global__ __launch_bounds__(256) void k_zero(int* p, int n) {
  int i = blockIdx.x * 256 + threadIdx.x;
  if (i < n) p[i] = 0;
}

__global__ __launch_bounds__(256) void k_count(const int* __restrict__ ei, int* __restrict__ cnt) {
  int t = blockIdx.x * 256 + threadIdx.x;
  if (t >= ETOT) return;
  int d = (t < EE) ? ei[EE + t] : (t - EE);
  atomicAdd(&cnt[d], 1);
}

__global__ __launch_bounds__(256) void k_scan(const int* __restrict__ cnt, int* __restrict__ offs) {
  __shared__ int part[256];
  int t = threadIdx.x;
  int loc[16]; int s = 0;
  #pragma unroll
  for (int i = 0; i < 16; ++i) { int v = cnt[(t << 4) + i]; loc[i] = s; s += v; }
  part[t] = s;
  __syncthreads();
  int own = s;
  for (int d = 1; d < 256; d <<= 1) {
    int u = (t >= d) ? part[t - d] : 0;
    __syncthreads();
    part[t] += u;
    __syncthreads();
  }
  int base = part[t] - own;
  #pragma unroll
  for (int i = 0; i < 16; ++i) offs[(t << 4) + i] = base + loc[i];
}

__global__ __launch_bounds__(256) void k_fill(const int* __restrict__ ei, const int* __restrict__ offs,
                                              int* __restrict__ cur, int* __restrict__ esrc) {
  int t = blockIdx.x * 256 + threadIdx.x;
  if (t >= ETOT) return;
  int s, d;
  if (t < EE) { s = ei[t]; d = ei[EE + t]; } else { s = d = t - EE; }
  int p = atomicAdd(&cur[d], 1);
  esrc[offs[d] + p] = s;
}

// ---------------- seq_linear: h = in^T @ Wseq + b + in^T  (+ fused HT write) ----------------
__global__ __launch_bounds__(256) void k_seq(const float* __restrict__ inp, const float* __restrict__ Wseq,
                                             const float* __restrict__ bseq, float* __restrict__ h,
                                             f16* __restrict__ HT) {
  __shared__ float X[64 * 68];
  int t = threadIdx.x;
  int b = blockIdx.x >> 6, n0 = (blockIdx.x & 63) << 6;
  #pragma unroll
  for (int i = 0; i < 16; ++i) {
    int idx = t + (i << 8);
    int s = idx >> 6, nl = idx & 63;
    X[nl * 68 + s] = inp[((size_t)((b << 6) + s) << 12) + n0 + nl];
  }
  __syncthreads();
  int c = t & 63, rg = t >> 6;
  float Wc[64];
  #pragma unroll
  for (int k = 0; k < 64; ++k) Wc[k] = Wseq[(k << 6) + c];
  float bc = bseq[c];
  float av[16];
  for (int rr = 0; rr < 16; ++rr) {
    int r = (rg << 4) + rr;
    float a = bc + X[r * 68 + c];
    #pragma unroll
    for (int k4 = 0; k4 < 16; ++k4) {
      float4 x = *(const float4*)&X[r * 68 + (k4 << 2)];
      a = fmaf(x.x, Wc[4*k4+0], a); a = fmaf(x.y, Wc[4*k4+1], a);
      a = fmaf(x.z, Wc[4*k4+2], a); a = fmaf(x.w, Wc[4*k4+3], a);
    }
    h[((size_t)(b << 12) + n0 + r) * 64 + c] = a;
    av[rr] = a;
  }
  __syncthreads();
  #pragma unroll
  for (int rr = 0; rr < 16; ++rr) X[((rg << 4) + rr) * 68 + c] = av[rr];
  __syncthreads();
  int nl = t & 63, dg = t >> 6;
  #pragma unroll
  for (int i = 0; i < 16; ++i) {
    int d = (dg << 4) + i;
    HT[((size_t)((b << 6) + d) << 12) + n0 + nl] = (f16)X[nl * 68 + d];
  }
}

// ---------------- adjacency prep: casts ----------------
__global__ __launch_bounds__(256) void k_castSE(const float* __restrict__ SE, f16* __restrict__ SEh) {
  int i = (blockIdx.x * 256 + threadIdx.x) * 4;
  float4 v = *(const float4*)(SE + i);
  f16 o[4] = {(f16)v.x, (f16)v.y, (f16)v.z, (f16)v.w};
  *(uint64_t*)(SEh + i) = *(uint64_t*)o;
}

__global__ __launch_bounds__(256) void k_castTE(const float* __restrict__ TE, f16* __restrict__ TEh) {
  __shared__ float X[64 * 65];
  int t = threadIdx.x;
  int j0 = blockIdx.x << 6;
  #pragma unroll
  for (int i = 0; i < 16; ++i) {
    int idx = t + (i << 8);           // 0..4095 = 64k x 64j
    int k = idx >> 6, jl = idx & 63;
    X[jl * 65 + k] = TE[((size_t)k << 12) + j0 + jl];
  }
  __syncthreads();
  int jl = t >> 2, kg = t & 3;        // 4 threads per output row, 16 k each
  f16 o[16];
  #pragma unroll
  for (int i = 0; i < 16; ++i) o[i] = (f16)X[jl * 65 + (kg << 4) + i];
  f16* dst = TEh + ((size_t)(j0 + jl) << 6) + (kg << 4);
  *(uint64_t*)(dst + 0) = *(uint64_t*)(o + 0);
  *(uint64_t*)(dst + 4) = *(uint64_t*)(o + 4);
  *(uint64_t*)(dst + 8) = *(uint64_t*)(o + 8);
  *(uint64_t*)(dst + 12) = *(uint64_t*)(o + 12);
}

// ---------------- adjacency MFMA GEMM: A = exp(relu(SEh @ TEh^T)) (raw), row partial sums ----------------
__global__ __launch_bounds__(256) void k_adjmm(const f16* __restrict__ SEh, const f16* __restrict__ TEh,
                                               f16* __restrict__ A, float* __restrict__ Zpart) {
  __shared__ f16 Al[128 * 32];
  __shared__ f16 Bl[128 * 32];
  const int t = threadIdx.x, lane = t & 63, w = t >> 6;
  const int m0 = blockIdx.y << 7, j0 = blockIdx.x << 7;
  const int l15 = lane & 15, lhi = lane >> 4;
  const int wm = (w >> 1) << 6, wj = (w & 1) << 6;
  f32x4 acc[4][4] = {};
  const int c0 = (w << 6) + lane;
  const int row0 = c0 >> 2, ko0 = (c0 & 3) << 3;
  const int c1 = c0 + 256;
  const int row1 = c1 >> 2, ko1 = (c1 & 3) << 3;
  const f16* ga0 = SEh + (size_t)(m0 + row0) * 64 + ko0;
  const f16* ga1 = SEh + (size_t)(m0 + row1) * 64 + ko1;
  const f16* gb0 = TEh + (size_t)(j0 + row0) * 64 + ko0;
  const f16* gb1 = TEh + (size_t)(j0 + row1) * 64 + ko1;
  f16* la0 = Al + c0 * 8; f16* la1 = Al + c1 * 8;
  f16* lb0 = Bl + c0 * 8; f16* lb1 = Bl + c1 * 8;
  for (int kt = 0; kt < 2; ++kt) {
    const int kof = kt << 5;
    gload16(ga0 + kof, la0);
    gload16(ga1 + kof, la1);
    gload16(gb0 + kof, lb0);
    gload16(gb1 + kof, lb1);
    __syncthreads();
    half8 af[4], bf[4];
    #pragma unroll
    for (int i = 0; i < 4; ++i) {
      af[i] = *(const half8*)(Al + (wm + i * 16 + l15) * 32 + lhi * 8);
      bf[i] = *(const half8*)(Bl + (wj + i * 16 + l15) * 32 + lhi * 8);
    }
    #pragma unroll
    for (int mi = 0; mi < 4; ++mi)
      #pragma unroll
      for (int nj = 0; nj < 4; ++nj)
        acc[mi][nj] = __builtin_amdgcn_mfma_f32_16x16x32_f16(af[mi], bf[nj], acc[mi][nj], 0, 0, 0);
    __syncthreads();
  }
  float rs[4][4];
  #pragma unroll
  for (int mi = 0; mi < 4; ++mi)
    #pragma unroll
    for (int r = 0; r < 4; ++r) rs[mi][r] = 0.f;
  #pragma unroll
  for (int mi = 0; mi < 4; ++mi)
    #pragma unroll
    for (int nj = 0; nj < 4; ++nj)
      #pragma unroll
      for (int r = 0; r < 4; ++r) {
        int row = m0 + wm + mi * 16 + lhi * 4 + r;
        int col = j0 + wj + nj * 16 + l15;
        float e = __expf(fmaxf(acc[mi][nj][r], 0.f));
        f16 eh = (f16)e;
        A[((size_t)row << 12) + col] = eh;
        rs[mi][r] += (float)eh;      // sum the rounded value for consistency
      }
  #pragma unroll
  for (int mi = 0; mi < 4; ++mi)
    #pragma unroll
    for (int r = 0; r < 4; ++r) {
      float s = rs[mi][r];
      s += __shfl_xor(s, 1); s += __shfl_xor(s, 2);
      s += __shfl_xor(s, 4); s += __shfl_xor(s, 8);
      rs[mi][r] = s;
    }
  if (l15 == 0) {
    int p = (blockIdx.x << 1) + (w & 1);
    #pragma unroll
    for (int mi = 0; mi < 4; ++mi)
      #pragma unroll
      for (int r = 0; r < 4; ++r)
        Zpart[((size_t)p << 12) + m0 + wm + mi * 16 + lhi * 4 + r] = rs[mi][r];
  }
}

__global__ __launch_bounds__(256) void k_rowz(const float* __restrict__ Zpart, float* __restrict__ rowZ) {
  int row = blockIdx.x * 256 + threadIdx.x;
  float s = 0.f;
  #pragma unroll 8
  for (int p = 0; p < 64; ++p) s += Zpart[((size_t)p << 12) + row];
  rowZ[row] = 1.f / s;
}

// ---------------- big GEMM, 8-phase-style schedule ----------------
// Cpart[m,j] = sum_k Araw[m,k]*BT[j,k], f16 partials, KSPLIT=2.
// BM=256 BN=128 BK=64; 512 thr (8 waves, 2x4); 3 LDS buffers (144KB dynamic), prefetch dist 2.
// Counted vmcnt(6) BEFORE end-of-tile barrier (never 0 mid-loop) -> loads span tiles.
// LDS slot-XOR swizzle (slot ^= row&7, bijective within each 128B row): conflict-free frag
// reads, global coalescing preserved (both-sides rule: pre-swizzled source + swizzled read).
#define NKT 32
__global__ __launch_bounds__(512) void k_gemm8(const f16* __restrict__ A, const f16* __restrict__ BT,
                                               f16* __restrict__ Cout) {
  extern __shared__ f16 smem[];     // 3 bufs x (A 16384 f16 + B 8192 f16) = 73728 f16
  const int t = threadIdx.x, lane = t & 63, wid = t >> 6;
  const int wr = wid >> 2, wc = wid & 3;
  const int l15 = lane & 15, lhi = lane >> 4;
  const int h7 = l15 & 7;
  const int wgid = blockIdx.x;
  const int nid = (wgid & 7) * 32 + (wgid >> 3);   // 256 wgs, 32 contiguous per XCD
  const int z = nid >> 7, rem = nid & 127;
  const int m0 = (rem >> 3) << 8;                  // 16 m-tiles * 256
  const int j0 = (rem & 7) << 7;                   // 8 j-tiles * 128
  const size_t kbase = (size_t)z << 11;            // K half
  f16* __restrict__ Cz = Cout + ((size_t)z << 22);

  // per-thread stage descriptors: A 4 loads, B 2 loads per K-tile
  const f16* gA[4]; int lA[4];
  #pragma unroll
  for (int i = 0; i < 4; ++i) {
    int s = t + (i << 9), row = s >> 3, sl = (s & 7) ^ (row & 7);
    gA[i] = A + (size_t)(m0 + row) * 4096 + kbase + sl * 8;
    lA[i] = s * 8;
  }
  const f16* gB[2]; int lB[2];
  #pragma unroll
  for (int i = 0; i < 2; ++i) {
    int s = t + (i << 9), row = s >> 3, sl = (s & 7) ^ (row & 7);
    gB[i] = BT + (size_t)(j0 + row) * 4096 + kbase + sl * 8;
    lB[i] = 16384 + s * 8;
  }
  #define SA(buf, kt, i) gload16(gA[i] + (kt) * 64, smem + (buf) * 24576 + lA[i])
  #define SB(buf, kt, i) gload16(gB[i] + (kt) * 64, smem + (buf) * 24576 + lB[i])

  const int rbase = wr << 7;    // wave rows: 128
  const int cbase = wc << 5;    // wave cols: 32
  f32x4 acc[8][2] = {};

  // prologue: stage tiles 0,1
  #pragma unroll
  for (int i = 0; i < 4; ++i) SA(0, 0, i);
  #pragma unroll
  for (int i = 0; i < 2; ++i) SB(0, 0, i);
  #pragma unroll
  for (int i = 0; i < 4; ++i) SA(1, 1, i);
  #pragma unroll
  for (int i = 0; i < 2; ++i) SB(1, 1, i);
  asm volatile("s_waitcnt vmcnt(6)" ::: "memory");   // own tile-0 loads retired
  __builtin_amdgcn_sched_barrier(0);
  __builtin_amdgcn_s_barrier();                      // collective: tile 0 ready
  __builtin_amdgcn_sched_barrier(0);

  int b0 = 0, b1 = 1, b2 = 2;
  for (int kt = 0; kt < NKT; ++kt) {
    const f16* Ab = smem + b0 * 24576;
    const f16* Bb = Ab + 16384;
    const bool pf = (kt + 2 < NKT);
    // ---- phase 0 (ks = 0) ----
    {
      half8 af[8], bf[2];
      #pragma unroll
      for (int mi = 0; mi < 8; ++mi) {
        int row = rbase + mi * 16 + l15;
        af[mi] = *(const half8*)(Ab + row * 64 + (lhi ^ h7) * 8);
      }
      #pragma unroll
      for (int nj = 0; nj < 2; ++nj) {
        int row = cbase + nj * 16 + l15;
        bf[nj] = *(const half8*)(Bb + row * 64 + (lhi ^ h7) * 8);
      }
      if (pf) { SA(b2, kt + 2, 0); SA(b2, kt + 2, 1); SA(b2, kt + 2, 2); }
      __builtin_amdgcn_s_setprio(1);
      #pragma unroll
      for (int mi = 0; mi < 8; ++mi)
        #pragma unroll
        for (int nj = 0; nj < 2; ++nj)
          acc[mi][nj] = __builtin_amdgcn_mfma_f32_16x16x32_f16(af[mi], bf[nj], acc[mi][nj], 0, 0, 0);
      __builtin_amdgcn_s_setprio(0);
    }
    __builtin_amdgcn_s_barrier();
    __builtin_amdgcn_sched_barrier(0);
    // ---- phase 1 (ks = 1) ----
    {
      half8 af[8], bf[2];
      #pragma unroll
      for (int mi = 0; mi < 8; ++mi) {
        int row = rbase + mi * 16 + l15;
        af[mi] = *(const half8*)(Ab + row * 64 + ((4 + lhi) ^ h7) * 8);
      }
      #pragma unroll
      for (int nj = 0; nj < 2; ++nj) {
        int row = cbase + nj * 16 + l15;
        bf[nj] = *(const half8*)(Bb + row * 64 + ((4 + lhi) ^ h7) * 8);
      }
      if (pf) { SA(b2, kt + 2, 3); SB(b2, kt + 2, 0); SB(b2, kt + 2, 1); }
      __builtin_amdgcn_s_setprio(1);
      #pragma unroll
      for (int mi = 0; mi < 8; ++mi)
        #pragma unroll
        for (int nj = 0; nj < 2; ++nj)
          acc[mi][nj] = __builtin_amdgcn_mfma_f32_16x16x32_f16(af[mi], bf[nj], acc[mi][nj], 0, 0, 0);
      __builtin_amdgcn_s_setprio(0);
    }
    // counted vmcnt BEFORE the barrier: own tile-(kt+1) loads retired -> after the
    // barrier all waves' tile-(kt+1) writes have landed. Never drains the kt+2 prefetch.
    if (kt < NKT - 2)       asm volatile("s_waitcnt vmcnt(6)" ::: "memory");
    else if (kt == NKT - 2) asm volatile("s_waitcnt vmcnt(0)" ::: "memory");
    __builtin_amdgcn_sched_barrier(0);
    __builtin_amdgcn_s_barrier();
    __builtin_amdgcn_sched_barrier(0);
    int tb = b0; b0 = b1; b1 = b2; b2 = tb;
  }
  #undef SA
  #undef SB
  // epilogue: f16 partial store
  #pragma unroll
  for (int mi = 0; mi < 8; ++mi)
    #pragma unroll
    for (int nj = 0; nj < 2; ++nj)
      #pragma unroll
      for (int r = 0; r < 4; ++r) {
        int row = m0 + rbase + mi * 16 + (lhi << 2) + r;
        int col = j0 + cbase + nj * 16 + l15;
        Cz[(size_t)row * 1024 + col] = (f16)acc[mi][nj][r];
      }
}

// ---------------- Wgh prep: B^T for xp-GEMM, padded with va/vd columns ----------------
template<int H, int NP>
__global__ __launch_bounds__(256) void k_wprep(const float* __restrict__ Wg, const float* __restrict__ asrc,
                                               const float* __restrict__ adst, f16* __restrict__ Wgh) {
  for (int i = blockIdx.x * 256 + threadIdx.x; i < NP * 64; i += 16 * 256) {
    int j = i >> 6, k = i & 63;
    float v;
    if (j < H * 64) {
      v = Wg[(size_t)k * (H * 64) + j];
    } else if (j < H * 64 + 2 * H) {
      int cc = j - H * 64, hh = cc >> 1;
      const float* a = ((cc & 1) ? adst : asrc) + (hh << 6);
      const float* wrow = Wg + (size_t)k * (H * 64) + (hh << 6);
      float s = 0.f;
      #pragma unroll 16
      for (int c = 0; c < 64; ++c) s = fmaf(wrow[c], a[c], s);
      v = s;
    } else v = 0.f;
    Wgh[(size_t)j * 64 + k] = (f16)v;
  }
}

// ---------------- xp = h @ Wg via MFMA (f16 out) + als/ald from padded columns ----------------
template<int H, int NP>
__global__ __launch_bounds__(256) void k_xpmm(const float* __restrict__ h, const f16* __restrict__ Wgh,
                                              f16* __restrict__ xp, float* __restrict__ als,
                                              float* __restrict__ ald) {
  __shared__ f16 Ah[128 * 72];
  __shared__ f16 Bh[NP * 72];
  const int t = threadIdx.x, lane = t & 63, w = t >> 6;
  const size_t r0 = (size_t)blockIdx.x * 128;
  #pragma unroll
  for (int i = 0; i < 8; ++i) {
    int idx = t + (i << 8);
    int row = idx >> 4, k4 = (idx & 15) << 2;
    float4 v = *(const float4*)&h[(r0 + row) * 64 + k4];
    f16 o[4] = {(f16)v.x, (f16)v.y, (f16)v.z, (f16)v.w};
    *(uint64_t*)&Ah[row * 72 + k4] = *(uint64_t*)o;
  }
  for (int i = t; i < NP * 16; i += 256) {
    int row = i >> 4, k4 = (i & 15) << 2;
    *(uint64_t*)&Bh[row * 72 + k4] = *(const uint64_t*)&Wgh[(size_t)row * 64 + k4];
  }
  __syncthreads();
  const int l15 = lane & 15, lhi = lane >> 4;
  const int NT = NP / 16;
  f32x4 acc[2][NT] = {};
  #pragma unroll
  for (int kk = 0; kk < 2; ++kk) {
    half8 af[2], bf[NT];
    #pragma unroll
    for (int i = 0; i < 2; ++i)
      af[i] = *(const half8*)&Ah[(w * 32 + i * 16 + l15) * 72 + kk * 32 + lhi * 8];
    #pragma unroll
    for (int j = 0; j < NT; ++j)
      bf[j] = *(const half8*)&Bh[(j * 16 + l15) * 72 + kk * 32 + lhi * 8];
    #pragma unroll
    for (int i = 0; i < 2; ++i)
      #pragma unroll
      for (int j = 0; j < NT; ++j)
        acc[i][j] = __builtin_amdgcn_mfma_f32_16x16x32_f16(af[i], bf[j], acc[i][j], 0, 0, 0);
  }
  #pragma unroll
  for (int i = 0; i < 2; ++i) {
    int rloc = w * 32 + i * 16 + lhi * 4;
    #pragma unroll
    for (int j = 0; j < NT; ++j) {
      #pragma unroll
      for (int r = 0; r < 4; ++r) {
        int col = j * 16 + l15;
        size_t row = r0 + rloc + r;
        float v = acc[i][j][r];
        if (j * 16 + 15 < H * 64) {
          xp[row * (H * 64) + col] = (f16)v;
        } else {
          if (col < H * 64) xp[row * (H * 64) + col] = (f16)v;
          else {
            int cc = col - H * 64;
            if (cc < 2 * H) {
              int hh = cc >> 1;
              if (cc & 1) ald[row * H + hh] = v; else als[row * H + hh] = v;
            }
          }
        }
      }
    }
  }
}

// ---------------- GAT aggregation: one wave per (b, node), lane-parallel softmax ----------------
template<int H>
__global__ __launch_bounds__(256) void k_agg(const f16* __restrict__ xp, const float* __restrict__ als,
                                             const float* __restrict__ ald,
                                             const int* __restrict__ offs, const int* __restrict__ cnt,
                                             const int* __restrict__ esrc, const float* __restrict__ bg,
                                             float* __restrict__ hcur) {
  __shared__ float wbuf[4][H * 64];
  __shared__ int   sbuf[4][64];
  int t = threadIdx.x, lane = t & 63, wv = t >> 6;
  int wid = (blockIdx.x << 2) + wv;
  int b = wid >> 12, n = wid & 4095;
  size_t rbase = (size_t)b << 12;
  int o = offs[n], c = cnt[n];
  float aldh[H], m[H], z[H], acc[H];
  #pragma unroll
  for (int hh = 0; hh < H; ++hh) {
    aldh[hh] = ald[(rbase + n) * H + hh];
    m[hh] = -1e30f; z[hh] = 0.f; acc[hh] = 0.f;
  }
  for (int e0 = 0; e0 < c; e0 += 64) {
    int ce = min(64, c - e0);
    float evl[H]; int sl = 0;
    if (lane < ce) {
      sl = esrc[o + e0 + lane];
      #pragma unroll
      for (int hh = 0; hh < H; ++hh) {
        float ev = als[(rbase + sl) * H + hh] + aldh[hh];
        evl[hh] = ev > 0.f ? ev : 0.2f * ev;
      }
    } else {
      #pragma unroll
      for (int hh = 0; hh < H; ++hh) evl[hh] = -1e30f;
    }
    sbuf[wv][lane] = sl;
    #pragma unroll
    for (int hh = 0; hh < H; ++hh) {
      float v = evl[hh];
      #pragma unroll
      for (int s = 1; s < 64; s <<= 1) v = fmaxf(v, __shfl_xor(v, s));
      float mn = fmaxf(m[hh], v);
      float sc = __expf(m[hh] - mn);
      z[hh] *= sc; acc[hh] *= sc; m[hh] = mn;
      float w = (lane < ce) ? __expf(evl[hh] - mn) : 0.f;
      wbuf[wv][hh * 64 + lane] = w;
      float zs = w;
      #pragma unroll
      for (int s = 1; s < 64; s <<= 1) zs += __shfl_xor(zs, s);
      z[hh] += zs;
    }
    for (int e = 0; e < ce; ++e) {
      int s = sbuf[wv][e];
      const f16* row = xp + (rbase + s) * (size_t)(H * 64) + lane;
      #pragma unroll
      for (int hh = 0; hh < H; ++hh)
        acc[hh] = fmaf(wbuf[wv][hh * 64 + e], (float)row[hh << 6], acc[hh]);
    }
  }
  float r = 0.f;
  #pragma unroll
  for (int hh = 0; hh < H; ++hh) r += acc[hh] / z[hh];
  hcur[(rbase + n) * 64 + lane] = r * (1.f / H) + bg[lane];
}

// ---------------- layer-0 combine (+ fused HT write); adp f16 partials * rowZ ----------------
__global__ __launch_bounds__(256) void k_comb0(const float* __restrict__ h, const f16* __restrict__ adp,
                                               const float* __restrict__ rowZ,
                                               const float* __restrict__ Wl, const float* __restrict__ bl,
                                               const float* __restrict__ Wo, const float* __restrict__ bo,
                                               float* __restrict__ hout, f16* __restrict__ HT) {
  __shared__ float Xa[64 * 68];
  __shared__ float Xh[64 * 68];
  int t = threadIdx.x;
  int b = blockIdx.x >> 6, n0 = (blockIdx.x & 63) << 6;
  #pragma unroll
  for (int i = 0; i < 4; ++i) {
    int idx = t + (i << 8);
    int nl = idx >> 4, d4 = (idx & 15) << 2;
    size_t arow = ((size_t)(n0 + nl) << 10) + (b << 6) + d4;
    float zi = rowZ[n0 + nl];
    float4 s = {0.f, 0.f, 0.f, 0.f};
    #pragma unroll
    for (int p = 0; p < KSPLIT; ++p) {
      f16x4 q = *(const f16x4*)&adp[arow + (size_t)p * (4096 * 1024)];
      s.x += (float)q[0]; s.y += (float)q[1]; s.z += (float)q[2]; s.w += (float)q[3];
    }
    s.x *= zi; s.y *= zi; s.z *= zi; s.w *= zi;
    *(float4*)&Xa[nl * 68 + d4] = s;
    *(float4*)&Xh[nl * 68 + d4] = *(const float4*)&h[((size_t)(b << 12) + n0 + nl) * 64 + d4];
  }
  __syncthreads();
  int c = t & 63, rg = t >> 6;
  float blc = bl[c], boc = bo[c];
  float Wc[64], gv[16], fv[16];
  #pragma unroll
  for (int k = 0; k < 64; ++k) Wc[k] = Wl[(k << 6) + c];
  for (int rr = 0; rr < 16; ++rr) {
    int r = (rg << 4) + rr;
    float ag = blc;
    #pragma unroll
    for (int k4 = 0; k4 < 16; ++k4) {
      float4 x = *(const float4*)&Xa[r * 68 + (k4 << 2)];
      ag = fmaf(x.x, Wc[4*k4+0], ag); ag = fmaf(x.y, Wc[4*k4+1], ag);
      ag = fmaf(x.z, Wc[4*k4+2], ag); ag = fmaf(x.w, Wc[4*k4+3], ag);
    }
    gv[rr] = 1.f / (1.f + __expf(-ag));
  }
  #pragma unroll
  for (int k = 0; k < 64; ++k) Wc[k] = Wo[(k << 6) + c];
  for (int rr = 0; rr < 16; ++rr) {
    int r = (rg << 4) + rr;
    float ao = boc;
    #pragma unroll
    for (int k4 = 0; k4 < 16; ++k4) {
      float4 x = *(const float4*)&Xh[r * 68 + (k4 << 2)];
      ao = fmaf(x.x, Wc[4*k4+0], ao); ao = fmaf(x.y, Wc[4*k4+1], ao);
      ao = fmaf(x.z, Wc[4*k4+2], ao); ao = fmaf(x.w, Wc[4*k4+3], ao);
    }
    float hv = Xh[r * 68 + c];
    float g = gv[rr];
    float val = tanhf(hv) * g + ao * (1.f - g);
    hout[((size_t)(b << 12) + n0 + r) * 64 + c] = val;
    fv[rr] = val;
  }
  __syncthreads();
  #pragma unroll
  for (int rr = 0; rr < 16; ++rr) Xh[((rg << 4) + rr) * 68 + c] = fv[rr];
  __syncthreads();
  int nl = t & 63, dg = t >> 6;
  #pragma unroll
  for (int i = 0; i < 16; ++i) {
    int d = (dg << 4) + i;
    HT[((size_t)((b << 6) + d) << 12) + n0 + nl] = (f16)Xh[nl * 68 + d];
  }
}

// ---------------- layer-1/2 combine (+ optional fused HT write); adp f16 partials * rowZ ----------------
template<int ACT, bool WRT>   // ACT 0: leaky 0.01, 1: relu
__global__ __launch_bounds__(256) void k_comb12(const float* __restrict__ h, const f16* __restrict__ adp,
                                                const float* __restrict__ rowZ,
                                                const float* __restrict__ hcur, const float* __restrict__ Wl,
                                                const float* __restrict__ bl, float* __restrict__ hout,
                                                f16* __restrict__ HT) {
  __shared__ float Xa[64 * 68];
  int t = threadIdx.x;
  int b = blockIdx.x >> 6, n0 = (blockIdx.x & 63) << 6;
  #pragma unroll
  for (int i = 0; i < 4; ++i) {
    int idx = t + (i << 8);
    int nl = idx >> 4, d4 = (idx & 15) << 2;
    size_t arow = ((size_t)(n0 + nl) << 10) + (b << 6) + d4;
    float zi = rowZ[n0 + nl];
    float4 s = {0.f, 0.f, 0.f, 0.f};
    #pragma unroll
    for (int p = 0; p < KSPLIT; ++p) {
      f16x4 q = *(const f16x4*)&adp[arow + (size_t)p * (4096 * 1024)];
      s.x += (float)q[0]; s.y += (float)q[1]; s.z += (float)q[2]; s.w += (float)q[3];
    }
    s.x *= zi; s.y *= zi; s.z *= zi; s.w *= zi;
    *(float4*)&Xa[nl * 68 + d4] = s;
  }
  __syncthreads();
  int c = t & 63, rg = t >> 6;
  float Wc[64];
  #pragma unroll
  for (int k = 0; k < 64; ++k) Wc[k] = Wl[(k << 6) + c];
  float blc = bl[c];
  float fv[16];
  for (int rr = 0; rr < 16; ++rr) {
    int r = (rg << 4) + rr;
    float ag = blc;
    #pragma unroll
    for (int k4 = 0; k4 < 16; ++k4) {
      float4 x = *(const float4*)&Xa[r * 68 + (k4 << 2)];
      ag = fmaf(x.x, Wc[4*k4+0], ag); ag = fmaf(x.y, Wc[4*k4+1], ag);
      ag = fmaf(x.z, Wc[4*k4+2], ag); ag = fmaf(x.w, Wc[4*k4+3], ag);
    }
    float g = 1.f / (1.f + __expf(-ag));
    size_t ridx = ((size_t)(b << 12) + n0 + r) * 64 + c;
    float hv = h[ridx], cv = hcur[ridx];
    float act = ACT ? fmaxf(cv, 0.f) : (cv > 0.f ? cv : 0.01f * cv);
    float val = act * g + hv * (1.f - g);
    hout[ridx] = val;
    fv[rr] = val;
  }
  if (WRT) {
    __syncthreads();
    #pragma unroll
    for (int rr = 0; rr < 16; ++rr) Xa[((rg << 4) + rr) * 68 + c] = fv[rr];
    __syncthreads();
    int nl = t & 63, dg = t >> 6;
    #pragma unroll
    for (int i = 0; i < 16; ++i) {
      int d = (dg << 4) + i;
      HT[((size_t)((b << 6) + d) << 12) + n0 + nl] = (f16)Xa[nl * 68 + d];
    }
  }
}

// ---------------- host launch ----------------
extern "C" void kernel_launch(void* const* d_in, const int* in_sizes, int n_in,
                              void* d_out, int out_size, void* d_ws, size_t ws_size,
                              hipStream_t stream) {
  (void)in_sizes; (void)n_in; (void)out_size; (void)ws_size;
  const float* inp  = (const float*)d_in[0];
  const int*   ei   = (const int*)d_in[1];
  const float* Wseq = (const float*)d_in[2];
  const float* bseq = (const float*)d_in[3];
  const float* SE   = (const float*)d_in[4];
  const float* TE   = (const float*)d_in[5];
  const float* Wg[3]   = {(const float*)d_in[6],  (const float*)d_in[12], (const float*)d_in[18]};
  const float* asrc[3] = {(const float*)d_in[7],  (const float*)d_in[13], (const float*)d_in[19]};
  const float* adst[3] = {(const float*)d_in[8],  (const float*)d_in[14], (const float*)d_in[20]};
  const float* bgp[3]  = {(const float*)d_in[9],  (const float*)d_in[15], (const float*)d_in[21]};
  const float* Wl[3]   = {(const float*)d_in[10], (const float*)d_in[16], (const float*)d_in[22]};
  const float* bl[3]   = {(const float*)d_in[11], (const float*)d_in[17], (const float*)d_in[23]};
  const float* Wo = (const float*)d_in[24];
  const float* bo = (const float*)d_in[25];
  float* out = (float*)d_out;

  uint8_t* ws = (uint8_t*)d_ws;
  size_t o = 0;
  auto nxt = [&](size_t sz) { void* p = ws + o; o += (sz + 255) & ~(size_t)255; return p; };
  f16*   Af   = (f16*)  nxt((size_t)NN * NN * sizeof(f16));        // 32 MB
  f16*   HT   = (f16*)  nxt((size_t)1024 * NN * sizeof(f16));      // 8 MB
  float* h    = (float*)nxt((size_t)ROWS * 64 * 4);                // 16 MB
  f16*   adp  = (f16*)  nxt((size_t)KSPLIT * NN * 1024 * sizeof(f16)); // 16 MB (2 f16 k-split parts)
  f16*   xp   = (f16*)  nxt((size_t)ROWS * 192 * sizeof(f16));     // 24 MB
  float* als  = (float*)nxt((size_t)ROWS * 3 * 4);
  float* ald  = (float*)nxt((size_t)ROWS * 3 * 4);
  float* hcur = (float*)nxt((size_t)ROWS * 64 * 4);                // 16 MB
  float* rowZ = (float*)nxt((size_t)NN * 4);
  float* Zpart= (float*)nxt((size_t)64 * NN * 4);                  // 1 MB
  f16*   SEh  = (f16*)  nxt((size_t)NN * 64 * sizeof(f16));
  f16*   TEh  = (f16*)  nxt((size_t)NN * 64 * sizeof(f16));
  f16*   Wgh  = (f16*)  nxt((size_t)256 * 64 * sizeof(f16));       // padded B^T for xp-GEMM
  int*   cnt  = (int*)  nxt((size_t)NN * 4);
  int*   curp = (int*)  nxt((size_t)NN * 4);
  int*   offs = (int*)  nxt((size_t)NN * 4);
  int*   esrc = (int*)  nxt((size_t)ETOT * 4);

  static bool attr_set = false;
  if (!attr_set) {
    hipFuncSetAttribute((const void*)k_gemm8, hipFuncAttributeMaxDynamicSharedMemorySize, 147456);
    attr_set = true;
  }

  dim3 blk(256);
  // CSR build
  k_zero<<<16, blk, 0, stream>>>(cnt, NN);
  k_zero<<<16, blk, 0, stream>>>(curp, NN);
  k_count<<<144, blk, 0, stream>>>(ei, cnt);
  k_scan<<<1, blk, 0, stream>>>(cnt, offs);
  k_fill<<<144, blk, 0, stream>>>(ei, offs, curp, esrc);
  // h0 (+HT) + adjacency (MFMA path, raw exp + rowZ)
  k_seq<<<1024, blk, 0, stream>>>(inp, Wseq, bseq, h, HT);
  k_castSE<<<256, blk, 0, stream>>>(SE, SEh);
  k_castTE<<<64, blk, 0, stream>>>(TE, TEh);
  k_adjmm<<<dim3(32, 32), blk, 0, stream>>>(SEh, TEh, Af, Zpart);
  k_rowz<<<16, blk, 0, stream>>>(Zpart, rowZ);
  // ---- layer 0 ----
  k_gemm8<<<256, 512, 147456, stream>>>(Af, HT, adp);
  k_comb0<<<1024, blk, 0, stream>>>(h, adp, rowZ, Wl[0], bl[0], Wo, bo, h, HT);
  // ---- layer 1 ----
  k_wprep<3, 208><<<16, blk, 0, stream>>>(Wg[1], asrc[1], adst[1], Wgh);
  k_xpmm<3, 208><<<512, blk, 0, stream>>>(h, Wgh, xp, als, ald);
  k_gemm8<<<256, 512, 147456, stream>>>(Af, HT, adp);
  k_agg<3><<<16384, blk, 0, stream>>>(xp, als, ald, offs, cnt, esrc, bgp[1], hcur);
  k_comb12<0, true><<<1024, blk, 0, stream>>>(h, adp, rowZ, hcur, Wl[1], bl[1], h, HT);
  // ---- layer 2 ----
  k_wprep<1, 80><<<16, blk, 0, stream>>>(Wg[2], asrc[2], adst[2], Wgh);
  k_xpmm<1, 80><<<512, blk, 0, stream>>>(h, Wgh, xp, als, ald);
  k_gemm8<<<256, 512, 147456, stream>>>(Af, HT, adp);
  k_agg<1><<<16384, blk, 0, stream>>>(xp, als, ald, offs, cnt, esrc, bgp[2], hcur);
  k_comb12<1, false><<<1024, blk, 0, stream>>>(h, adp, rowZ, hcur, Wl[2], bl[2], out, (f16*)nullptr);
}